// Round 5
// baseline (288.256 us; speedup 1.0000x reference)
//
#include <hip/hip_runtime.h>
#include <math.h>

#define EDIM 768
#define NH 12
#define HD 64
#define BSZ 8
#define NN 512
#define NCAT 1664          // 768(q) + 768(k) + 36(vw) padded to 13*128

typedef short short8 __attribute__((ext_vector_type(8)));
typedef float f32x4 __attribute__((ext_vector_type(4)));

__device__ __forceinline__ unsigned short f2bf(float x) {
    unsigned int u = __float_as_uint(x);
    u = (u + 0x7FFF + ((u >> 16) & 1)) >> 16;   // RNE
    return (unsigned short)u;
}
__device__ __forceinline__ float bf2f(unsigned short s) {
    return __uint_as_float(((unsigned int)s) << 16);
}
__device__ __forceinline__ void gl2lds16(const void* g, void* l) {
    __builtin_amdgcn_global_load_lds(
        (const __attribute__((address_space(1))) unsigned int*)g,
        (__attribute__((address_space(3))) unsigned int*)l, 16, 0, 0);
}

// ---- prep block ranges ----
#define PB_GEOM_END 512          // 8*64 geometry blocks
#define PB_TR_END   1664         // +1152: WT transpose for q/k (48 n-tiles x 24 e-tiles)
#define PB_VW_END   1772         // +108: WT vw columns (36*768/256)
#define PB_CVT_END  3308         // +1536: X fp32->bf16 (4096*96/256)
#define PB_BC_END   3315         // +7: bcat
#define PREP_BLOCKS 3350         // +35: WT padding rows zero

// ---------------- K1: fused prep ----------------
__global__ __launch_bounds__(256) void k_prep(
        const float* __restrict__ query, const float* __restrict__ pos,
        const float* __restrict__ Wq, const float* __restrict__ bq,
        const float* __restrict__ Wk, const float* __restrict__ bk,
        const float* __restrict__ Wv, const float* __restrict__ bv,
        const float* __restrict__ W1, const float* __restrict__ W2,
        const float* __restrict__ W3,
        unsigned short* __restrict__ WT, float* __restrict__ bcat,
        unsigned short* __restrict__ Xb,
        unsigned short* __restrict__ ud0, unsigned short* __restrict__ ud1,
        unsigned short* __restrict__ ud2) {
    __shared__ float sm[1536];
    const int bid = blockIdx.x;
    const int t = threadIdx.x;

    if (bid < PB_GEOM_END) {
        // geometry: ud_c[b][i][j] = delta_c/(dist+eps) bf16
        float* psx = sm; float* psy = sm + NN; float* psz = sm + 2 * NN;
        const int b = bid >> 6, i0 = (bid & 63) * 8;
        for (int idx = t; idx < NN; idx += 256) {
            const float* p = pos + ((size_t)b * NN + idx) * 3;
            psx[idx] = p[0]; psy[idx] = p[1]; psz[idx] = p[2];
        }
        __syncthreads();
        const int i = i0 + (t >> 5);
        const float qx = psx[i], qy = psy[i], qz = psz[i];
        const size_t row = ((size_t)b * NN + i) * NN;
        for (int jt = 0; jt < 4; jt++) {
            int j = ((t & 31) + jt * 32) * 4;
            unsigned short s0[4], s1[4], s2[4];
            #pragma unroll
            for (int u = 0; u < 4; u++) {
                float dx = psx[j + u] - qx, dy = psy[j + u] - qy, dz = psz[j + u] - qz;
                float inv = 1.f / (sqrtf(dx * dx + dy * dy + dz * dz) + 1e-5f);
                s0[u] = f2bf(dx * inv); s1[u] = f2bf(dy * inv); s2[u] = f2bf(dz * inv);
            }
            *(uint2*)&ud0[row + j] = make_uint2(s0[0] | ((unsigned)s0[1] << 16), s0[2] | ((unsigned)s0[3] << 16));
            *(uint2*)&ud1[row + j] = make_uint2(s1[0] | ((unsigned)s1[1] << 16), s1[2] | ((unsigned)s1[3] << 16));
            *(uint2*)&ud2[row + j] = make_uint2(s2[0] | ((unsigned)s2[1] << 16), s2[2] | ((unsigned)s2[3] << 16));
        }
    } else if (bid < PB_TR_END) {
        // WT[n][e] = W{q,k}[e][n mod 768] bf16, via LDS transpose
        float (*tile)[33] = (float(*)[33])sm;
        const int tb = bid - PB_GEOM_END;
        const int n0 = (tb % 48) * 32, e0 = (tb / 48) * 32;
        const float* src = (n0 < 768) ? Wq : Wk;
        const int ol0 = (n0 < 768) ? n0 : (n0 - 768);   // FIX: 768 not pow2, & 767 was wrong
        const int tx = t & 31, ty = t >> 5;
        #pragma unroll
        for (int s = 0; s < 4; s++)
            tile[ty + s * 8][tx] = src[(size_t)(e0 + ty + s * 8) * EDIM + ol0 + tx];
        __syncthreads();
        #pragma unroll
        for (int s = 0; s < 4; s++)
            WT[(size_t)(n0 + ty + s * 8) * EDIM + e0 + tx] = f2bf(tile[tx][ty + s * 8]);
    } else if (bid < PB_VW_END) {
        // WT vw columns: WT[1536+o2][e] = sum_d Wv[e][h*64+d]*Wc[h*64+d]
        int idx = (bid - PB_TR_END) * 256 + t;   // < 27648
        int o2 = idx / 768, e = idx - o2 * 768;
        int h = o2 / 3, c = o2 - (o2 / 3) * 3;
        const float* Wc = (c == 0) ? W1 : (c == 1) ? W2 : W3;
        float s = 0.f;
        #pragma unroll 8
        for (int d = 0; d < HD; d++) s += Wv[(size_t)e * EDIM + h * HD + d] * Wc[h * HD + d];
        WT[(size_t)(1536 + o2) * EDIM + e] = f2bf(s);
    } else if (bid < PB_CVT_END) {
        // X fp32 (n,b,e) -> Xb[m][e] bf16
        int idx = (bid - PB_VW_END) * 256 + t;   // < 393216
        int m = idx / 96, e8 = (idx - (idx / 96) * 96) * 8;
        int b = m >> 9, i = m & (NN - 1);
        const float* src = query + ((size_t)i * BSZ + b) * EDIM + e8;
        float4 v0 = *(const float4*)src;
        float4 v1 = *(const float4*)(src + 4);
        unsigned int p0 = f2bf(v0.x) | ((unsigned int)f2bf(v0.y) << 16);
        unsigned int p1 = f2bf(v0.z) | ((unsigned int)f2bf(v0.w) << 16);
        unsigned int p2 = f2bf(v1.x) | ((unsigned int)f2bf(v1.y) << 16);
        unsigned int p3 = f2bf(v1.z) | ((unsigned int)f2bf(v1.w) << 16);
        uint4 pk = {p0, p1, p2, p3};
        *(uint4*)&Xb[(size_t)idx * 8] = pk;
    } else if (bid < PB_BC_END) {
        int o = (bid - PB_CVT_END) * 256 + t;
        if (o < NCAT) {
            float v = 0.f;
            if (o < 768) v = bq[o];
            else if (o < 1536) v = bk[o - 768];
            else if (o < 1572) {
                int o2 = o - 1536;
                int h = o2 / 3, c = o2 - (o2 / 3) * 3;
                const float* Wc = (c == 0) ? W1 : (c == 1) ? W2 : W3;
                float s = 0.f;
                for (int d = 0; d < HD; d++) s += bv[h * HD + d] * Wc[h * HD + d];
                v = s;
            }
            bcat[o] = v;
        }
    } else {
        int tid = (bid - PB_BC_END) * 256 + t;
        if (tid < 8832) {
            uint4 z = {0, 0, 0, 0};
            *(uint4*)&WT[(size_t)1572 * EDIM + (size_t)tid * 8] = z;
        }
    }
}

// ---------------- K2: bf16 MFMA GEMM (64x128 tile, bit-identical K-chain to 128x128) ----------------
__global__ __launch_bounds__(256) void k_gemm_qkv(
        const unsigned short* __restrict__ Xb, const unsigned short* __restrict__ WT,
        const float* __restrict__ bcat,
        unsigned short* __restrict__ qb, unsigned short* __restrict__ kb,
        float* __restrict__ vwb) {
    __shared__ short As[8 * 64 * 8];    // 8 KB
    __shared__ short Bs[8 * 128 * 8];   // 16 KB
    const int t = threadIdx.x;
    const int m0 = blockIdx.x * 64, n0 = blockIdx.y * 128;
    const int w = t >> 6, lane = t & 63, quad = lane >> 4, ln = lane & 15;
    const int wm = (w & 1) * 32, wn = (w >> 1) * 64;

    f32x4 acc[2][4];
    #pragma unroll
    for (int mi = 0; mi < 2; mi++)
        #pragma unroll
        for (int ni = 0; ni < 4; ni++) acc[mi][ni] = (f32x4){0.f, 0.f, 0.f, 0.f};

    for (int k0 = 0; k0 < EDIM; k0 += 64) {
        __syncthreads();
        #pragma unroll
        for (int is = 0; is < 2; is++) {
            int slot = is * 256 + t;
            int g = slot >> 6, m = slot & 63;
            gl2lds16(Xb + (size_t)(m0 + m) * EDIM + k0 + g * 8, &As[(size_t)(is * 256 + w * 64) * 8]);
        }
        #pragma unroll
        for (int is = 0; is < 4; is++) {
            int slot = is * 256 + t;
            int g = slot >> 7, n = slot & 127;
            gl2lds16(WT + (size_t)(n0 + n) * EDIM + k0 + g * 8, &Bs[(size_t)(is * 256 + w * 64) * 8]);
        }
        __syncthreads();
        #pragma unroll
        for (int s = 0; s < 2; s++) {
            short8 af[2], bf[4];
            #pragma unroll
            for (int mi = 0; mi < 2; mi++)
                af[mi] = *(const short8*)&As[(size_t)((s * 4 + quad) * 64 + wm + mi * 16 + ln) * 8];
            #pragma unroll
            for (int ni = 0; ni < 4; ni++)
                bf[ni] = *(const short8*)&Bs[(size_t)((s * 4 + quad) * 128 + wn + ni * 16 + ln) * 8];
            #pragma unroll
            for (int mi = 0; mi < 2; mi++)
                #pragma unroll
                for (int ni = 0; ni < 4; ni++)
                    acc[mi][ni] = __builtin_amdgcn_mfma_f32_16x16x32_bf16(af[mi], bf[ni], acc[mi][ni], 0, 0, 0);
        }
    }

    #pragma unroll
    for (int mi = 0; mi < 2; mi++) {
        #pragma unroll
        for (int r = 0; r < 4; r++) {
            int mg = m0 + wm + mi * 16 + quad * 4 + r;
            int b_ = mg >> 9, i_ = mg & (NN - 1);
            #pragma unroll
            for (int ni = 0; ni < 4; ni++) {
                int o = n0 + wn + ni * 16 + ln;
                float val = acc[mi][ni][r] + bcat[o];
                if (o < 768) {
                    int h = o >> 6, d = o & 63;
                    qb[(((size_t)b_ * NH + h) * NN + i_) * HD + d] = f2bf(val * 0.125f);
                } else if (o < 1536) {
                    int o2 = o - 768;
                    int h = o2 >> 6, d = o2 & 63;
                    kb[(((size_t)b_ * NH + h) * NN + i_) * HD + d] = f2bf(val);
                } else if (o < 1572) {
                    int o2 = o - 1536;
                    int h = o2 / 3, c = o2 - (o2 / 3) * 3;
                    vwb[(((size_t)b_ * NH + h) * NN + i_) * 3 + c] = val;
                }
            }
        }
    }
}

// ---------------- K3: attention partials (j-quarter per block, deterministic slots) ----------------
__global__ __launch_bounds__(256) void k_attn(
        const unsigned short* __restrict__ qb, const unsigned short* __restrict__ kb,
        const float* __restrict__ vwb, const float* __restrict__ bias,
        const unsigned short* __restrict__ ud0, const unsigned short* __restrict__ ud1,
        const unsigned short* __restrict__ ud2,
        float* __restrict__ mp, float* __restrict__ lp,
        float* __restrict__ a0p, float* __restrict__ a1p, float* __restrict__ a2p) {
    __shared__ short Ks[8 * 64 * 8];    // 8 KB
    __shared__ float ws0[NN], ws1[NN], ws2[NN];

    const int t = threadIdx.x;
    const int bid = blockIdx.x;
    const int h = bid % NH;
    const int r1 = bid / NH;            // [0,256)
    const int js = r1 & 3;
    const int it = (r1 >> 2) & 7;
    const int b = r1 >> 5;
    const int i0 = it * 64;
    const int jb = js * 128;
    const int w = t >> 6, lane = t & 63, quad = lane >> 4, ln = lane & 15;
    const size_t bh = (size_t)b * NH + h;

    for (int idx = t; idx < NN * 3; idx += 256) {
        float v = vwb[bh * (NN * 3) + idx];
        int j = idx / 3, c = idx - (idx / 3) * 3;
        if (c == 0) ws0[j] = v; else if (c == 1) ws1[j] = v; else ws2[j] = v;
    }

    const int ig = i0 + w * 16 + ln;
    const unsigned short* qrow = qb + (bh * NN + ig) * HD;
    short8 qf0 = *(const short8*)(qrow + quad * 8);
    short8 qf1 = *(const short8*)(qrow + 32 + quad * 8);
    const float* brow = bias + (bh * NN + ig) * NN;
    const size_t udrow = ((size_t)b * NN + ig) * NN;

    float m_r = -3.0e38f, l_r = 0.f, a0 = 0.f, a1 = 0.f, a2 = 0.f;

    for (int jt = 0; jt < 2; jt++) {
        const int j0 = jb + jt * 64;
        __syncthreads();
        #pragma unroll
        for (int is = 0; is < 2; is++) {
            int slot = is * 256 + t;
            int dg = slot >> 6, j = slot & 63;
            gl2lds16(kb + (bh * NN + j0 + j) * HD + dg * 8, &Ks[(size_t)(is * 256 + w * 64) * 8]);
        }
        __syncthreads();

        f32x4 acc[4];
        #pragma unroll
        for (int sub = 0; sub < 4; sub++) {
            short8 af0 = *(const short8*)&Ks[(size_t)(quad * 64 + sub * 16 + ln) * 8];
            short8 af1 = *(const short8*)&Ks[(size_t)((4 + quad) * 64 + sub * 16 + ln) * 8];
            f32x4 z = {0.f, 0.f, 0.f, 0.f};
            z = __builtin_amdgcn_mfma_f32_16x16x32_bf16(af0, qf0, z, 0, 0, 0);
            z = __builtin_amdgcn_mfma_f32_16x16x32_bf16(af1, qf1, z, 0, 0, 0);
            acc[sub] = z;
        }

        float sv[16];
        #pragma unroll
        for (int sub = 0; sub < 4; sub++) {
            f32x4 bv = *(const f32x4*)(brow + j0 + sub * 16 + quad * 4);
            sv[sub * 4 + 0] = acc[sub][0] + bv[0];
            sv[sub * 4 + 1] = acc[sub][1] + bv[1];
            sv[sub * 4 + 2] = acc[sub][2] + bv[2];
            sv[sub * 4 + 3] = acc[sub][3] + bv[3];
        }
        float lm = sv[0];
        #pragma unroll
        for (int u = 1; u < 16; u++) lm = fmaxf(lm, sv[u]);
        float mn = fmaxf(m_r, lm);
        float alpha = __expf(m_r - mn);
        float lps = 0.f, s0 = 0.f, s1 = 0.f, s2 = 0.f;
        #pragma unroll
        for (int sub = 0; sub < 4; sub++) {
            int j = j0 + sub * 16 + quad * 4;
            f32x4 w0v = *(const f32x4*)&ws0[j];
            f32x4 w1v = *(const f32x4*)&ws1[j];
            f32x4 w2v = *(const f32x4*)&ws2[j];
            union { uint2 u; unsigned short s[4]; } U0, U1, U2;
            U0.u = *(const uint2*)&ud0[udrow + j];
            U1.u = *(const uint2*)&ud1[udrow + j];
            U2.u = *(const uint2*)&ud2[udrow + j];
            #pragma unroll
            for (int r = 0; r < 4; r++) {
                float p = __expf(sv[sub * 4 + r] - mn);
                lps += p;
                s0 = fmaf(p * bf2f(U0.s[r]), w0v[r], s0);
                s1 = fmaf(p * bf2f(U1.s[r]), w1v[r], s1);
                s2 = fmaf(p * bf2f(U2.s[r]), w2v[r], s2);
            }
        }
        l_r = l_r * alpha + lps;
        a0 = a0 * alpha + s0;
        a1 = a1 * alpha + s1;
        a2 = a2 * alpha + s2;
        m_r = mn;
    }

    // merge the 4 quad partials
    #pragma unroll
    for (int off = 16; off <= 32; off <<= 1) {
        float mo = __shfl_xor(m_r, off, 64);
        float lo = __shfl_xor(l_r, off, 64);
        float b0 = __shfl_xor(a0, off, 64);
        float b1 = __shfl_xor(a1, off, 64);
        float b2 = __shfl_xor(a2, off, 64);
        float mn = fmaxf(m_r, mo);
        float e1 = __expf(m_r - mn), e2 = __expf(mo - mn);
        l_r = l_r * e1 + lo * e2;
        a0 = a0 * e1 + b0 * e2;
        a1 = a1 * e1 + b1 * e2;
        a2 = a2 * e1 + b2 * e2;
        m_r = mn;
    }
    if (quad == 0) {
        size_t o4 = (bh * NN + ig) * 4 + js;
        mp[o4] = m_r; lp[o4] = l_r;
        a0p[o4] = a0; a1p[o4] = a1; a2p[o4] = a2;
    }
}

// ---------------- K4: finalize — exact max-merge over js, sum heads ----------------
__global__ __launch_bounds__(256) void k_finalize(
        const float* __restrict__ mp, const float* __restrict__ lp,
        const float* __restrict__ a0p, const float* __restrict__ a1p,
        const float* __restrict__ a2p,
        const float* __restrict__ b1, const float* __restrict__ b2,
        const float* __restrict__ b3, float* __restrict__ out) {
    int idx = blockIdx.x * 256 + threadIdx.x;   // 4096
    int b = idx >> 9, i = idx & (NN - 1);
    float s0 = 0.f, s1 = 0.f, s2 = 0.f;
    #pragma unroll
    for (int h = 0; h < NH; h++) {
        size_t base = (((size_t)b * NH + h) * NN + i) * 4;
        f32x4 mv = *(const f32x4*)&mp[base];
        f32x4 lv = *(const f32x4*)&lp[base];
        f32x4 A0 = *(const f32x4*)&a0p[base];
        f32x4 A1 = *(const f32x4*)&a1p[base];
        f32x4 A2 = *(const f32x4*)&a2p[base];
        float M = fmaxf(fmaxf(mv[0], mv[1]), fmaxf(mv[2], mv[3]));
        float L = 0.f, c0 = 0.f, c1 = 0.f, c2 = 0.f;
        #pragma unroll
        for (int js = 0; js < 4; js++) {
            float e = __expf(mv[js] - M);
            L = fmaf(e, lv[js], L);
            c0 = fmaf(e, A0[js], c0);
            c1 = fmaf(e, A1[js], c1);
            c2 = fmaf(e, A2[js], c2);
        }
        float inv = 1.f / L;
        s0 = fmaf(c0, inv, s0);
        s1 = fmaf(c1, inv, s1);
        s2 = fmaf(c2, inv, s2);
    }
    float* op = out + (size_t)idx * 3;
    op[0] = s0 + b1[0];
    op[1] = s1 + b2[0];
    op[2] = s2 + b3[0];
}

extern "C" void kernel_launch(void* const* d_in, const int* in_sizes, int n_in,
                              void* d_out, int out_size, void* d_ws, size_t ws_size,
                              hipStream_t stream) {
    const float* query = (const float*)d_in[0];
    const float* bias  = (const float*)d_in[1];
    const float* pos   = (const float*)d_in[2];
    const float* Wq = (const float*)d_in[3];
    const float* bq = (const float*)d_in[4];
    const float* Wk = (const float*)d_in[5];
    const float* bk = (const float*)d_in[6];
    const float* Wv = (const float*)d_in[7];
    const float* bv = (const float*)d_in[8];
    const float* W1 = (const float*)d_in[9];
    const float* b1 = (const float*)d_in[10];
    const float* W2 = (const float*)d_in[11];
    const float* b2 = (const float*)d_in[12];
    const float* W3 = (const float*)d_in[13];
    const float* b3 = (const float*)d_in[14];
    float* out = (float*)d_out;

    char* p = (char*)d_ws;
    unsigned short* WT = (unsigned short*)p; p += (size_t)NCAT * EDIM * 2;      // 2.6 MB
    float* bcat = (float*)p;                 p += (size_t)NCAT * 4;
    unsigned short* Xb = (unsigned short*)p; p += (size_t)BSZ * NN * EDIM * 2;  // 6.3 MB
    unsigned short* qb = (unsigned short*)p; p += (size_t)BSZ * NH * NN * HD * 2;
    unsigned short* kb = (unsigned short*)p; p += (size_t)BSZ * NH * NN * HD * 2;
    float* vwb = (float*)p;                  p += (size_t)BSZ * NH * NN * 3 * 4;
    unsigned short* ud0 = (unsigned short*)p; p += (size_t)BSZ * NN * NN * 2;
    unsigned short* ud1 = (unsigned short*)p; p += (size_t)BSZ * NN * NN * 2;
    unsigned short* ud2 = (unsigned short*)p; p += (size_t)BSZ * NN * NN * 2;
    const size_t PSZ = (size_t)BSZ * NH * NN * 4;   // partial slots (b,h,i,js)
    float* mp  = (float*)p; p += PSZ * 4;
    float* lp  = (float*)p; p += PSZ * 4;
    float* a0p = (float*)p; p += PSZ * 4;
    float* a1p = (float*)p; p += PSZ * 4;
    float* a2p = (float*)p; p += PSZ * 4;

    k_prep<<<PREP_BLOCKS, 256, 0, stream>>>(query, pos, Wq, bq, Wk, bk, Wv, bv,
                                            W1, W2, W3, WT, bcat, Xb, ud0, ud1, ud2);
    dim3 g2(64, 13);
    k_gemm_qkv<<<g2, 256, 0, stream>>>(Xb, WT, bcat, qb, kb, vwb);
    k_attn<<<BSZ * NH * 8 * 4, 256, 0, stream>>>(qb, kb, vwb, bias, ud0, ud1, ud2,
                                                 mp, lp, a0p, a1p, a2p);
    k_finalize<<<BSZ * NN / 256, 256, 0, stream>>>(mp, lp, a0p, a1p, a2p, b1, b2, b3, out);
}

// Round 6
// 281.336 us; speedup vs baseline: 1.0246x; 1.0246x over previous
//
#include <hip/hip_runtime.h>
#include <math.h>

#define EDIM 768
#define NH 12
#define HD 64
#define BSZ 8
#define NN 512
#define NCAT 1664          // 768(q) + 768(k) + 36(vw) padded to 13*128

typedef short short8 __attribute__((ext_vector_type(8)));
typedef float f32x4 __attribute__((ext_vector_type(4)));

__device__ __forceinline__ unsigned short f2bf(float x) {
    unsigned int u = __float_as_uint(x);
    u = (u + 0x7FFF + ((u >> 16) & 1)) >> 16;   // RNE
    return (unsigned short)u;
}
__device__ __forceinline__ float bf2f(unsigned short s) {
    return __uint_as_float(((unsigned int)s) << 16);
}
__device__ __forceinline__ void gl2lds16(const void* g, void* l) {
    __builtin_amdgcn_global_load_lds(
        (const __attribute__((address_space(1))) unsigned int*)g,
        (__attribute__((address_space(3))) unsigned int*)l, 16, 0, 0);
}

// ---- prep block ranges ----
#define PB_GEOM_END 512          // 8*64 geometry blocks
#define PB_TR_END   1664         // +1152: WT transpose for q/k (48 n-tiles x 24 e-tiles)
#define PB_VW_END   1772         // +108: WT vw columns (36*768/256)
#define PB_CVT_END  3308         // +1536: X fp32->bf16 (4096*96/256)
#define PB_BC_END   3315         // +7: bcat
#define PREP_BLOCKS 3350         // +35: WT padding rows zero

// ---------------- K1: fused prep ----------------
__global__ __launch_bounds__(256) void k_prep(
        const float* __restrict__ query, const float* __restrict__ pos,
        const float* __restrict__ Wq, const float* __restrict__ bq,
        const float* __restrict__ Wk, const float* __restrict__ bk,
        const float* __restrict__ Wv, const float* __restrict__ bv,
        const float* __restrict__ W1, const float* __restrict__ W2,
        const float* __restrict__ W3,
        unsigned short* __restrict__ WT, float* __restrict__ bcat,
        unsigned short* __restrict__ Xb,
        unsigned short* __restrict__ ud0, unsigned short* __restrict__ ud1,
        unsigned short* __restrict__ ud2) {
    __shared__ float sm[1536];
    const int bid = blockIdx.x;
    const int t = threadIdx.x;

    if (bid < PB_GEOM_END) {
        // geometry: ud_c[b][i][j] = delta_c/(dist+eps) bf16
        float* psx = sm; float* psy = sm + NN; float* psz = sm + 2 * NN;
        const int b = bid >> 6, i0 = (bid & 63) * 8;
        for (int idx = t; idx < NN; idx += 256) {
            const float* p = pos + ((size_t)b * NN + idx) * 3;
            psx[idx] = p[0]; psy[idx] = p[1]; psz[idx] = p[2];
        }
        __syncthreads();
        const int i = i0 + (t >> 5);
        const float qx = psx[i], qy = psy[i], qz = psz[i];
        const size_t row = ((size_t)b * NN + i) * NN;
        for (int jt = 0; jt < 4; jt++) {
            int j = ((t & 31) + jt * 32) * 4;
            unsigned short s0[4], s1[4], s2[4];
            #pragma unroll
            for (int u = 0; u < 4; u++) {
                float dx = psx[j + u] - qx, dy = psy[j + u] - qy, dz = psz[j + u] - qz;
                float inv = 1.f / (sqrtf(dx * dx + dy * dy + dz * dz) + 1e-5f);
                s0[u] = f2bf(dx * inv); s1[u] = f2bf(dy * inv); s2[u] = f2bf(dz * inv);
            }
            *(uint2*)&ud0[row + j] = make_uint2(s0[0] | ((unsigned)s0[1] << 16), s0[2] | ((unsigned)s0[3] << 16));
            *(uint2*)&ud1[row + j] = make_uint2(s1[0] | ((unsigned)s1[1] << 16), s1[2] | ((unsigned)s1[3] << 16));
            *(uint2*)&ud2[row + j] = make_uint2(s2[0] | ((unsigned)s2[1] << 16), s2[2] | ((unsigned)s2[3] << 16));
        }
    } else if (bid < PB_TR_END) {
        // WT[n][e] = W{q,k}[e][n mod 768] bf16, via LDS transpose
        float (*tile)[33] = (float(*)[33])sm;
        const int tb = bid - PB_GEOM_END;
        const int n0 = (tb % 48) * 32, e0 = (tb / 48) * 32;
        const float* src = (n0 < 768) ? Wq : Wk;
        const int ol0 = (n0 < 768) ? n0 : (n0 - 768);
        const int tx = t & 31, ty = t >> 5;
        #pragma unroll
        for (int s = 0; s < 4; s++)
            tile[ty + s * 8][tx] = src[(size_t)(e0 + ty + s * 8) * EDIM + ol0 + tx];
        __syncthreads();
        #pragma unroll
        for (int s = 0; s < 4; s++)
            WT[(size_t)(n0 + ty + s * 8) * EDIM + e0 + tx] = f2bf(tile[tx][ty + s * 8]);
    } else if (bid < PB_VW_END) {
        // WT vw columns: WT[1536+o2][e] = sum_d Wv[e][h*64+d]*Wc[h*64+d]
        int idx = (bid - PB_TR_END) * 256 + t;   // < 27648
        int o2 = idx / 768, e = idx - o2 * 768;
        int h = o2 / 3, c = o2 - (o2 / 3) * 3;
        const float* Wc = (c == 0) ? W1 : (c == 1) ? W2 : W3;
        const float4* wvp = (const float4*)(Wv + (size_t)e * EDIM + h * HD);
        const float4* wcp = (const float4*)(Wc + h * HD);
        float s = 0.f;
        #pragma unroll
        for (int d4 = 0; d4 < 16; d4++) {
            float4 a = wvp[d4], b = wcp[d4];
            s += a.x * b.x + a.y * b.y + a.z * b.z + a.w * b.w;
        }
        WT[(size_t)(1536 + o2) * EDIM + e] = f2bf(s);
    } else if (bid < PB_CVT_END) {
        // X fp32 (n,b,e) -> Xb[m][e] bf16
        int idx = (bid - PB_VW_END) * 256 + t;   // < 393216
        int m = idx / 96, e8 = (idx - (idx / 96) * 96) * 8;
        int b = m >> 9, i = m & (NN - 1);
        const float* src = query + ((size_t)i * BSZ + b) * EDIM + e8;
        float4 v0 = *(const float4*)src;
        float4 v1 = *(const float4*)(src + 4);
        unsigned int p0 = f2bf(v0.x) | ((unsigned int)f2bf(v0.y) << 16);
        unsigned int p1 = f2bf(v0.z) | ((unsigned int)f2bf(v0.w) << 16);
        unsigned int p2 = f2bf(v1.x) | ((unsigned int)f2bf(v1.y) << 16);
        unsigned int p3 = f2bf(v1.z) | ((unsigned int)f2bf(v1.w) << 16);
        uint4 pk = {p0, p1, p2, p3};
        *(uint4*)&Xb[(size_t)idx * 8] = pk;
    } else if (bid < PB_BC_END) {
        int o = (bid - PB_CVT_END) * 256 + t;
        if (o < NCAT) {
            float v = 0.f;
            if (o < 768) v = bq[o];
            else if (o < 1536) v = bk[o - 768];
            else if (o < 1572) {
                int o2 = o - 1536;
                int h = o2 / 3, c = o2 - (o2 / 3) * 3;
                const float* Wc = (c == 0) ? W1 : (c == 1) ? W2 : W3;
                float s = 0.f;
                for (int d = 0; d < HD; d++) s += bv[h * HD + d] * Wc[h * HD + d];
                v = s;
            }
            bcat[o] = v;
        }
    } else {
        int tid = (bid - PB_BC_END) * 256 + t;
        if (tid < 8832) {
            uint4 z = {0, 0, 0, 0};
            *(uint4*)&WT[(size_t)1572 * EDIM + (size_t)tid * 8] = z;
        }
    }
}

// ---------------- K2: bf16 MFMA GEMM (64x128 tile) ----------------
__global__ __launch_bounds__(256) void k_gemm_qkv(
        const unsigned short* __restrict__ Xb, const unsigned short* __restrict__ WT,
        const float* __restrict__ bcat,
        unsigned short* __restrict__ qb, unsigned short* __restrict__ kb,
        float* __restrict__ vwb) {
    __shared__ short As[8 * 64 * 8];    // 8 KB
    __shared__ short Bs[8 * 128 * 8];   // 16 KB
    const int t = threadIdx.x;
    const int m0 = blockIdx.x * 64, n0 = blockIdx.y * 128;
    const int w = t >> 6, lane = t & 63, quad = lane >> 4, ln = lane & 15;
    const int wm = (w & 1) * 32, wn = (w >> 1) * 64;

    f32x4 acc[2][4];
    #pragma unroll
    for (int mi = 0; mi < 2; mi++)
        #pragma unroll
        for (int ni = 0; ni < 4; ni++) acc[mi][ni] = (f32x4){0.f, 0.f, 0.f, 0.f};

    for (int k0 = 0; k0 < EDIM; k0 += 64) {
        __syncthreads();
        #pragma unroll
        for (int is = 0; is < 2; is++) {
            int slot = is * 256 + t;
            int g = slot >> 6, m = slot & 63;
            gl2lds16(Xb + (size_t)(m0 + m) * EDIM + k0 + g * 8, &As[(size_t)(is * 256 + w * 64) * 8]);
        }
        #pragma unroll
        for (int is = 0; is < 4; is++) {
            int slot = is * 256 + t;
            int g = slot >> 7, n = slot & 127;
            gl2lds16(WT + (size_t)(n0 + n) * EDIM + k0 + g * 8, &Bs[(size_t)(is * 256 + w * 64) * 8]);
        }
        __syncthreads();
        #pragma unroll
        for (int s = 0; s < 2; s++) {
            short8 af[2], bf[4];
            #pragma unroll
            for (int mi = 0; mi < 2; mi++)
                af[mi] = *(const short8*)&As[(size_t)((s * 4 + quad) * 64 + wm + mi * 16 + ln) * 8];
            #pragma unroll
            for (int ni = 0; ni < 4; ni++)
                bf[ni] = *(const short8*)&Bs[(size_t)((s * 4 + quad) * 128 + wn + ni * 16 + ln) * 8];
            #pragma unroll
            for (int mi = 0; mi < 2; mi++)
                #pragma unroll
                for (int ni = 0; ni < 4; ni++)
                    acc[mi][ni] = __builtin_amdgcn_mfma_f32_16x16x32_bf16(af[mi], bf[ni], acc[mi][ni], 0, 0, 0);
        }
    }

    #pragma unroll
    for (int mi = 0; mi < 2; mi++) {
        #pragma unroll
        for (int r = 0; r < 4; r++) {
            int mg = m0 + wm + mi * 16 + quad * 4 + r;
            int b_ = mg >> 9, i_ = mg & (NN - 1);
            #pragma unroll
            for (int ni = 0; ni < 4; ni++) {
                int o = n0 + wn + ni * 16 + ln;
                float val = acc[mi][ni][r] + bcat[o];
                if (o < 768) {
                    int h = o >> 6, d = o & 63;
                    qb[(((size_t)b_ * NH + h) * NN + i_) * HD + d] = f2bf(val * 0.125f);
                } else if (o < 1536) {
                    int o2 = o - 768;
                    int h = o2 >> 6, d = o2 & 63;
                    kb[(((size_t)b_ * NH + h) * NN + i_) * HD + d] = f2bf(val);
                } else if (o < 1572) {
                    int o2 = o - 1536;
                    int h = o2 / 3, c = o2 - (o2 / 3) * 3;
                    vwb[(((size_t)b_ * NH + h) * NN + i_) * 3 + c] = val;
                }
            }
        }
    }
}

// ---------------- K3: attention partials — single-barrier, bias-in-accumulator ----------------
// block = (h, js, it, b): 64 i x 128 j. Stage both Ks tiles + ws slice, prefetch
// bias into MFMA acc; one __syncthreads; MFMA; single-pass softmax; slot write.
__global__ __launch_bounds__(256, 4) void k_attn(
        const unsigned short* __restrict__ qb, const unsigned short* __restrict__ kb,
        const float* __restrict__ vwb, const float* __restrict__ bias,
        const unsigned short* __restrict__ ud0, const unsigned short* __restrict__ ud1,
        const unsigned short* __restrict__ ud2,
        float* __restrict__ mp, float* __restrict__ lp,
        float* __restrict__ a0p, float* __restrict__ a1p, float* __restrict__ a2p) {
    __shared__ short Ks[2 * 8 * 64 * 8];   // 16 KB: [tile][dgrp][j][8]
    __shared__ float ws0[128], ws1[128], ws2[128];

    const int t = threadIdx.x;
    const int bid = blockIdx.x;
    const int h = bid % NH;
    const int r1 = bid / NH;            // [0,256)
    const int js = r1 & 3;
    const int it = (r1 >> 2) & 7;
    const int b = r1 >> 5;
    const int i0 = it * 64;
    const int jb = js * 128;
    const int w = t >> 6, lane = t & 63, quad = lane >> 4, ln = lane & 15;
    const size_t bh = (size_t)b * NH + h;

    // stage both Ks tiles (1024 slots of 16B)
    #pragma unroll
    for (int is = 0; is < 4; is++) {
        int slot = is * 256 + t;
        int tile = slot >> 9, dg = (slot >> 6) & 7, j = slot & 63;
        gl2lds16(kb + (bh * NN + jb + tile * 64 + j) * HD + dg * 8,
                 &Ks[(size_t)(is * 256 + w * 64) * 8]);
    }
    // stage ws slice (128 j's x 3 channels, coalesced read)
    for (int idx = t; idx < 384; idx += 256) {
        float v = vwb[bh * (NN * 3) + (size_t)jb * 3 + idx];
        int jj = idx / 3, c = idx - (idx / 3) * 3;
        if (c == 0) ws0[jj] = v; else if (c == 1) ws1[jj] = v; else ws2[jj] = v;
    }

    const int ig = i0 + w * 16 + ln;
    const unsigned short* qrow = qb + (bh * NN + ig) * HD;
    short8 qf0 = *(const short8*)(qrow + quad * 8);
    short8 qf1 = *(const short8*)(qrow + 32 + quad * 8);
    const float* brow = bias + (bh * NN + ig) * NN + jb;
    const size_t udrow = ((size_t)b * NN + ig) * NN + jb;

    // bias preloaded directly into MFMA accumulators (C row = quad*4+r matches)
    f32x4 acc[8];
    #pragma unroll
    for (int s8 = 0; s8 < 8; s8++) {
        int off = (s8 >> 2) * 64 + (s8 & 3) * 16 + quad * 4;
        acc[s8] = *(const f32x4*)(brow + off);
    }

    __syncthreads();

    #pragma unroll
    for (int s8 = 0; s8 < 8; s8++) {
        int tile = s8 >> 2, sub = s8 & 3;
        short8 af0 = *(const short8*)&Ks[(size_t)((tile * 8 + quad) * 64 + sub * 16 + ln) * 8];
        short8 af1 = *(const short8*)&Ks[(size_t)((tile * 8 + 4 + quad) * 64 + sub * 16 + ln) * 8];
        acc[s8] = __builtin_amdgcn_mfma_f32_16x16x32_bf16(af0, qf0, acc[s8], 0, 0, 0);
        acc[s8] = __builtin_amdgcn_mfma_f32_16x16x32_bf16(af1, qf1, acc[s8], 0, 0, 0);
    }

    // single-pass softmax partial over this block's 128 j's
    float m_r = acc[0][0];
    #pragma unroll
    for (int s8 = 0; s8 < 8; s8++)
        #pragma unroll
        for (int r = 0; r < 4; r++) m_r = fmaxf(m_r, acc[s8][r]);
    m_r = fmaxf(m_r, __shfl_xor(m_r, 16, 64));
    m_r = fmaxf(m_r, __shfl_xor(m_r, 32, 64));

    float l_r = 0.f, a0 = 0.f, a1 = 0.f, a2 = 0.f;
    #pragma unroll
    for (int s8 = 0; s8 < 8; s8++) {
        int off = (s8 >> 2) * 64 + (s8 & 3) * 16 + quad * 4;
        f32x4 w0v = *(const f32x4*)&ws0[off];
        f32x4 w1v = *(const f32x4*)&ws1[off];
        f32x4 w2v = *(const f32x4*)&ws2[off];
        union { uint2 u; unsigned short s[4]; } U0, U1, U2;
        U0.u = *(const uint2*)&ud0[udrow + off];
        U1.u = *(const uint2*)&ud1[udrow + off];
        U2.u = *(const uint2*)&ud2[udrow + off];
        #pragma unroll
        for (int r = 0; r < 4; r++) {
            float p = __expf(acc[s8][r] - m_r);
            l_r += p;
            a0 = fmaf(p * bf2f(U0.s[r]), w0v[r], a0);
            a1 = fmaf(p * bf2f(U1.s[r]), w1v[r], a1);
            a2 = fmaf(p * bf2f(U2.s[r]), w2v[r], a2);
        }
    }

    // merge the 4 quad partials (shared max already)
    #pragma unroll
    for (int off = 16; off <= 32; off <<= 1) {
        l_r += __shfl_xor(l_r, off, 64);
        a0  += __shfl_xor(a0, off, 64);
        a1  += __shfl_xor(a1, off, 64);
        a2  += __shfl_xor(a2, off, 64);
    }
    if (quad == 0) {
        size_t o4 = (bh * NN + ig) * 4 + js;
        mp[o4] = m_r; lp[o4] = l_r;
        a0p[o4] = a0; a1p[o4] = a1; a2p[o4] = a2;
    }
}

// ---------------- K4: finalize — exact max-merge over js, sum heads ----------------
__global__ __launch_bounds__(256) void k_finalize(
        const float* __restrict__ mp, const float* __restrict__ lp,
        const float* __restrict__ a0p, const float* __restrict__ a1p,
        const float* __restrict__ a2p,
        const float* __restrict__ b1, const float* __restrict__ b2,
        const float* __restrict__ b3, float* __restrict__ out) {
    int idx = blockIdx.x * 256 + threadIdx.x;   // 4096
    int b = idx >> 9, i = idx & (NN - 1);
    float s0 = 0.f, s1 = 0.f, s2 = 0.f;
    #pragma unroll
    for (int h = 0; h < NH; h++) {
        size_t base = (((size_t)b * NH + h) * NN + i) * 4;
        f32x4 mv = *(const f32x4*)&mp[base];
        f32x4 lv = *(const f32x4*)&lp[base];
        f32x4 A0 = *(const f32x4*)&a0p[base];
        f32x4 A1 = *(const f32x4*)&a1p[base];
        f32x4 A2 = *(const f32x4*)&a2p[base];
        float M = fmaxf(fmaxf(mv[0], mv[1]), fmaxf(mv[2], mv[3]));
        float L = 0.f, c0 = 0.f, c1 = 0.f, c2 = 0.f;
        #pragma unroll
        for (int js = 0; js < 4; js++) {
            float e = __expf(mv[js] - M);
            L = fmaf(e, lv[js], L);
            c0 = fmaf(e, A0[js], c0);
            c1 = fmaf(e, A1[js], c1);
            c2 = fmaf(e, A2[js], c2);
        }
        float inv = 1.f / L;
        s0 = fmaf(c0, inv, s0);
        s1 = fmaf(c1, inv, s1);
        s2 = fmaf(c2, inv, s2);
    }
    float* op = out + (size_t)idx * 3;
    op[0] = s0 + b1[0];
    op[1] = s1 + b2[0];
    op[2] = s2 + b3[0];
}

extern "C" void kernel_launch(void* const* d_in, const int* in_sizes, int n_in,
                              void* d_out, int out_size, void* d_ws, size_t ws_size,
                              hipStream_t stream) {
    const float* query = (const float*)d_in[0];
    const float* bias  = (const float*)d_in[1];
    const float* pos   = (const float*)d_in[2];
    const float* Wq = (const float*)d_in[3];
    const float* bq = (const float*)d_in[4];
    const float* Wk = (const float*)d_in[5];
    const float* bk = (const float*)d_in[6];
    const float* Wv = (const float*)d_in[7];
    const float* bv = (const float*)d_in[8];
    const float* W1 = (const float*)d_in[9];
    const float* b1 = (const float*)d_in[10];
    const float* W2 = (const float*)d_in[11];
    const float* b2 = (const float*)d_in[12];
    const float* W3 = (const float*)d_in[13];
    const float* b3 = (const float*)d_in[14];
    float* out = (float*)d_out;

    char* p = (char*)d_ws;
    unsigned short* WT = (unsigned short*)p; p += (size_t)NCAT * EDIM * 2;      // 2.6 MB
    float* bcat = (float*)p;                 p += (size_t)NCAT * 4;
    unsigned short* Xb = (unsigned short*)p; p += (size_t)BSZ * NN * EDIM * 2;  // 6.3 MB
    unsigned short* qb = (unsigned short*)p; p += (size_t)BSZ * NH * NN * HD * 2;
    unsigned short* kb = (unsigned short*)p; p += (size_t)BSZ * NH * NN * HD * 2;
    float* vwb = (float*)p;                  p += (size_t)BSZ * NH * NN * 3 * 4;
    unsigned short* ud0 = (unsigned short*)p; p += (size_t)BSZ * NN * NN * 2;
    unsigned short* ud1 = (unsigned short*)p; p += (size_t)BSZ * NN * NN * 2;
    unsigned short* ud2 = (unsigned short*)p; p += (size_t)BSZ * NN * NN * 2;
    const size_t PSZ = (size_t)BSZ * NH * NN * 4;   // partial slots (b,h,i,js)
    float* mp  = (float*)p; p += PSZ * 4;
    float* lp  = (float*)p; p += PSZ * 4;
    float* a0p = (float*)p; p += PSZ * 4;
    float* a1p = (float*)p; p += PSZ * 4;
    float* a2p = (float*)p; p += PSZ * 4;

    k_prep<<<PREP_BLOCKS, 256, 0, stream>>>(query, pos, Wq, bq, Wk, bk, Wv, bv,
                                            W1, W2, W3, WT, bcat, Xb, ud0, ud1, ud2);
    dim3 g2(64, 13);
    k_gemm_qkv<<<g2, 256, 0, stream>>>(Xb, WT, bcat, qb, kb, vwb);
    k_attn<<<BSZ * NH * 8 * 4, 256, 0, stream>>>(qb, kb, vwb, bias, ud0, ud1, ud2,
                                                 mp, lp, a0p, a1p, a2p);
    k_finalize<<<BSZ * NN / 256, 256, 0, stream>>>(mp, lp, a0p, a1p, a2p, b1, b2, b3, out);
}

// Round 7
// 252.124 us; speedup vs baseline: 1.1433x; 1.1159x over previous
//
#include <hip/hip_runtime.h>
#include <math.h>

#define EDIM 768
#define NH 12
#define HD 64
#define BSZ 8
#define NN 512
#define NCAT 1664          // 768(q) + 768(k) + 36(vw) padded to 13*128

typedef short short8 __attribute__((ext_vector_type(8)));
typedef float f32x4 __attribute__((ext_vector_type(4)));

__device__ __forceinline__ unsigned short f2bf(float x) {
    unsigned int u = __float_as_uint(x);
    u = (u + 0x7FFF + ((u >> 16) & 1)) >> 16;   // RNE
    return (unsigned short)u;
}
__device__ __forceinline__ float bf2f(unsigned short s) {
    return __uint_as_float(((unsigned int)s) << 16);
}
__device__ __forceinline__ void gl2lds16(const void* g, void* l) {
    __builtin_amdgcn_global_load_lds(
        (const __attribute__((address_space(1))) unsigned int*)g,
        (__attribute__((address_space(3))) unsigned int*)l, 16, 0, 0);
}

// ---- prep block ranges ----
#define PB_GEOM_END 512          // 8*64 geometry blocks
#define PB_TR_END   1664         // +1152: WT transpose for q/k (48 n-tiles x 24 e-tiles)
#define PB_VW_END   1772         // +108: WT vw columns (36*768/256)
#define PB_CVT_END  3308         // +1536: X fp32->bf16 (4096*96/256)
#define PB_BC_END   3315         // +7: bcat
#define PREP_BLOCKS 3350         // +35: WT padding rows zero

// ---------------- K1: fused prep ----------------
__global__ __launch_bounds__(256) void k_prep(
        const float* __restrict__ query, const float* __restrict__ pos,
        const float* __restrict__ Wq, const float* __restrict__ bq,
        const float* __restrict__ Wk, const float* __restrict__ bk,
        const float* __restrict__ Wv, const float* __restrict__ bv,
        const float* __restrict__ W1, const float* __restrict__ W2,
        const float* __restrict__ W3,
        unsigned short* __restrict__ WT, float* __restrict__ bcat,
        unsigned short* __restrict__ Xb,
        unsigned int* __restrict__ udp) {
    __shared__ float sm[1536];
    const int bid = blockIdx.x;
    const int t = threadIdx.x;

    if (bid < PB_GEOM_END) {
        // geometry: udp[(b,i,j)] = {ud0,ud1,ud2,0} bf16x4 (8 B)
        float* psx = sm; float* psy = sm + NN; float* psz = sm + 2 * NN;
        const int b = bid >> 6, i0 = (bid & 63) * 8;
        for (int idx = t; idx < NN; idx += 256) {
            const float* p = pos + ((size_t)b * NN + idx) * 3;
            psx[idx] = p[0]; psy[idx] = p[1]; psz[idx] = p[2];
        }
        __syncthreads();
        const int i = i0 + (t >> 5);
        const float qx = psx[i], qy = psy[i], qz = psz[i];
        const size_t row = ((size_t)b * NN + i) * NN;
        for (int jt = 0; jt < 4; jt++) {
            int j = ((t & 31) + jt * 32) * 4;
            unsigned int s0[4], s1[4], s2[4];
            #pragma unroll
            for (int u = 0; u < 4; u++) {
                float dx = psx[j + u] - qx, dy = psy[j + u] - qy, dz = psz[j + u] - qz;
                float inv = 1.f / (sqrtf(dx * dx + dy * dy + dz * dz) + 1e-5f);
                s0[u] = f2bf(dx * inv); s1[u] = f2bf(dy * inv); s2[u] = f2bf(dz * inv);
            }
            uint4 A = {s0[0] | (s1[0] << 16), s2[0], s0[1] | (s1[1] << 16), s2[1]};
            uint4 B = {s0[2] | (s1[2] << 16), s2[2], s0[3] | (s1[3] << 16), s2[3]};
            *(uint4*)&udp[(row + j) * 2]     = A;
            *(uint4*)&udp[(row + j) * 2 + 4] = B;
        }
    } else if (bid < PB_TR_END) {
        // WT[n][e] = W{q,k}[e][n mod 768] bf16, via LDS transpose
        float (*tile)[33] = (float(*)[33])sm;
        const int tb = bid - PB_GEOM_END;
        const int n0 = (tb % 48) * 32, e0 = (tb / 48) * 32;
        const float* src = (n0 < 768) ? Wq : Wk;
        const int ol0 = (n0 < 768) ? n0 : (n0 - 768);
        const int tx = t & 31, ty = t >> 5;
        #pragma unroll
        for (int s = 0; s < 4; s++)
            tile[ty + s * 8][tx] = src[(size_t)(e0 + ty + s * 8) * EDIM + ol0 + tx];
        __syncthreads();
        #pragma unroll
        for (int s = 0; s < 4; s++)
            WT[(size_t)(n0 + ty + s * 8) * EDIM + e0 + tx] = f2bf(tile[tx][ty + s * 8]);
    } else if (bid < PB_VW_END) {
        // WT vw columns: WT[1536+o2][e] = sum_d Wv[e][h*64+d]*Wc[h*64+d]
        int idx = (bid - PB_TR_END) * 256 + t;   // < 27648
        int o2 = idx / 768, e = idx - o2 * 768;
        int h = o2 / 3, c = o2 - (o2 / 3) * 3;
        const float* Wc = (c == 0) ? W1 : (c == 1) ? W2 : W3;
        const float4* wvp = (const float4*)(Wv + (size_t)e * EDIM + h * HD);
        const float4* wcp = (const float4*)(Wc + h * HD);
        float s = 0.f;
        #pragma unroll
        for (int d4 = 0; d4 < 16; d4++) {
            float4 a = wvp[d4], b = wcp[d4];
            s += a.x * b.x + a.y * b.y + a.z * b.z + a.w * b.w;
        }
        WT[(size_t)(1536 + o2) * EDIM + e] = f2bf(s);
    } else if (bid < PB_CVT_END) {
        // X fp32 (n,b,e) -> Xb[m][e] bf16
        int idx = (bid - PB_VW_END) * 256 + t;   // < 393216
        int m = idx / 96, e8 = (idx - (idx / 96) * 96) * 8;
        int b = m >> 9, i = m & (NN - 1);
        const float* src = query + ((size_t)i * BSZ + b) * EDIM + e8;
        float4 v0 = *(const float4*)src;
        float4 v1 = *(const float4*)(src + 4);
        unsigned int p0 = f2bf(v0.x) | ((unsigned int)f2bf(v0.y) << 16);
        unsigned int p1 = f2bf(v0.z) | ((unsigned int)f2bf(v0.w) << 16);
        unsigned int p2 = f2bf(v1.x) | ((unsigned int)f2bf(v1.y) << 16);
        unsigned int p3 = f2bf(v1.z) | ((unsigned int)f2bf(v1.w) << 16);
        uint4 pk = {p0, p1, p2, p3};
        *(uint4*)&Xb[(size_t)idx * 8] = pk;
    } else if (bid < PB_BC_END) {
        int o = (bid - PB_CVT_END) * 256 + t;
        if (o < NCAT) {
            float v = 0.f;
            if (o < 768) v = bq[o];
            else if (o < 1536) v = bk[o - 768];
            else if (o < 1572) {
                int o2 = o - 1536;
                int h = o2 / 3, c = o2 - (o2 / 3) * 3;
                const float* Wc = (c == 0) ? W1 : (c == 1) ? W2 : W3;
                float s = 0.f;
                for (int d = 0; d < HD; d++) s += bv[h * HD + d] * Wc[h * HD + d];
                v = s;
            }
            bcat[o] = v;
        }
    } else {
        int tid = (bid - PB_BC_END) * 256 + t;
        if (tid < 8832) {
            uint4 z = {0, 0, 0, 0};
            *(uint4*)&WT[(size_t)1572 * EDIM + (size_t)tid * 8] = z;
        }
    }
}

// ---------------- K2: bf16 MFMA GEMM (64x128 tile) ----------------
__global__ __launch_bounds__(256) void k_gemm_qkv(
        const unsigned short* __restrict__ Xb, const unsigned short* __restrict__ WT,
        const float* __restrict__ bcat,
        unsigned short* __restrict__ qb, unsigned short* __restrict__ kb,
        float* __restrict__ vwb) {
    __shared__ short As[8 * 64 * 8];    // 8 KB
    __shared__ short Bs[8 * 128 * 8];   // 16 KB
    const int t = threadIdx.x;
    const int m0 = blockIdx.x * 64, n0 = blockIdx.y * 128;
    const int w = t >> 6, lane = t & 63, quad = lane >> 4, ln = lane & 15;
    const int wm = (w & 1) * 32, wn = (w >> 1) * 64;

    f32x4 acc[2][4];
    #pragma unroll
    for (int mi = 0; mi < 2; mi++)
        #pragma unroll
        for (int ni = 0; ni < 4; ni++) acc[mi][ni] = (f32x4){0.f, 0.f, 0.f, 0.f};

    for (int k0 = 0; k0 < EDIM; k0 += 64) {
        __syncthreads();
        #pragma unroll
        for (int is = 0; is < 2; is++) {
            int slot = is * 256 + t;
            int g = slot >> 6, m = slot & 63;
            gl2lds16(Xb + (size_t)(m0 + m) * EDIM + k0 + g * 8, &As[(size_t)(is * 256 + w * 64) * 8]);
        }
        #pragma unroll
        for (int is = 0; is < 4; is++) {
            int slot = is * 256 + t;
            int g = slot >> 7, n = slot & 127;
            gl2lds16(WT + (size_t)(n0 + n) * EDIM + k0 + g * 8, &Bs[(size_t)(is * 256 + w * 64) * 8]);
        }
        __syncthreads();
        #pragma unroll
        for (int s = 0; s < 2; s++) {
            short8 af[2], bf[4];
            #pragma unroll
            for (int mi = 0; mi < 2; mi++)
                af[mi] = *(const short8*)&As[(size_t)((s * 4 + quad) * 64 + wm + mi * 16 + ln) * 8];
            #pragma unroll
            for (int ni = 0; ni < 4; ni++)
                bf[ni] = *(const short8*)&Bs[(size_t)((s * 4 + quad) * 128 + wn + ni * 16 + ln) * 8];
            #pragma unroll
            for (int mi = 0; mi < 2; mi++)
                #pragma unroll
                for (int ni = 0; ni < 4; ni++)
                    acc[mi][ni] = __builtin_amdgcn_mfma_f32_16x16x32_bf16(af[mi], bf[ni], acc[mi][ni], 0, 0, 0);
        }
    }

    #pragma unroll
    for (int mi = 0; mi < 2; mi++) {
        #pragma unroll
        for (int r = 0; r < 4; r++) {
            int mg = m0 + wm + mi * 16 + quad * 4 + r;
            int b_ = mg >> 9, i_ = mg & (NN - 1);
            #pragma unroll
            for (int ni = 0; ni < 4; ni++) {
                int o = n0 + wn + ni * 16 + ln;
                float val = acc[mi][ni][r] + bcat[o];
                if (o < 768) {
                    int h = o >> 6, d = o & 63;
                    qb[(((size_t)b_ * NH + h) * NN + i_) * HD + d] = f2bf(val * 0.125f);
                } else if (o < 1536) {
                    int o2 = o - 768;
                    int h = o2 >> 6, d = o2 & 63;
                    kb[(((size_t)b_ * NH + h) * NN + i_) * HD + d] = f2bf(val);
                } else if (o < 1572) {
                    int o2 = o - 1536;
                    int h = o2 / 3, c = o2 - (o2 / 3) * 3;
                    vwb[(((size_t)b_ * NH + h) * NN + i_) * 3 + c] = val;
                }
            }
        }
    }
}

// ---------------- K3: attention partials — normal orientation (lane = j) ----------------
// block = (h, js, it, b): 64 i x 128 j. Wave wi owns i-sub16 x all 128 j.
// A=Q, B=K -> C row = i = quad*4+r, col = j = ln: bias/ud reads lane-coalesced.
__global__ __launch_bounds__(256, 4) void k_attn(
        const unsigned short* __restrict__ qb, const unsigned short* __restrict__ kb,
        const float* __restrict__ vwb, const float* __restrict__ bias,
        const unsigned int* __restrict__ udp,
        float* __restrict__ mp, float* __restrict__ lp,
        float* __restrict__ a0p, float* __restrict__ a1p, float* __restrict__ a2p) {
    __shared__ uint4 Qs[64 * 8];    // 8 KB, unit = row*8 + (c ^ (row&7))
    __shared__ uint4 Ks[128 * 8];   // 16 KB, same swizzle
    __shared__ float ws0[128], ws1[128], ws2[128];

    const int t = threadIdx.x;
    const int bid = blockIdx.x;
    const int h = bid % NH;
    const int r1 = bid / NH;            // [0,256)
    const int js = r1 & 3;
    const int it = (r1 >> 2) & 7;
    const int b = r1 >> 5;
    const int i0 = it * 64;
    const int jb = js * 128;
    const int w = t >> 6, lane = t & 63, quad = lane >> 4, ln = lane & 15;
    const size_t bh = (size_t)b * NH + h;

    // ---- coalesced global loads of Q (64x64) and K (128x64) tiles ----
    const uint4* qg = (const uint4*)(qb + (bh * NN + i0) * HD);   // 512 units
    const uint4* kg = (const uint4*)(kb + (bh * NN + jb) * HD);   // 1024 units
    const int rr = t >> 3, cc = t & 7;
    uint4 qv0 = qg[t];
    uint4 qv1 = qg[256 + t];
    uint4 kv0 = kg[t];
    uint4 kv1 = kg[256 + t];
    uint4 kv2 = kg[512 + t];
    uint4 kv3 = kg[768 + t];
    float wv0 = vwb[bh * (NN * 3) + (size_t)jb * 3 + t];
    float wv1 = (t < 128) ? vwb[bh * (NN * 3) + (size_t)jb * 3 + 256 + t] : 0.f;

    // ---- bias straight into MFMA accumulators (coalesced: 16 lanes x 4 rows) ----
    const float* bbase = bias + (bh * NN + i0 + w * 16 + quad * 4) * NN + jb + ln;
    f32x4 acc[8];
    #pragma unroll
    for (int jsub = 0; jsub < 8; jsub++)
        #pragma unroll
        for (int r = 0; r < 4; r++)
            acc[jsub][r] = bbase[r * NN + jsub * 16];

    // ---- LDS writes (xor-swizzled) ----
    const int sw = cc ^ (rr & 7);
    Qs[rr * 8 + sw] = qv0;
    Qs[(rr + 32) * 8 + sw] = qv1;
    Ks[rr * 8 + sw] = kv0;
    Ks[(rr + 32) * 8 + sw] = kv1;
    Ks[(rr + 64) * 8 + sw] = kv2;
    Ks[(rr + 96) * 8 + sw] = kv3;
    {
        int jj = t / 3, c = t - (t / 3) * 3;
        if (c == 0) ws0[jj] = wv0; else if (c == 1) ws1[jj] = wv0; else ws2[jj] = wv0;
        if (t < 128) {
            int t2 = 256 + t;
            int jj2 = t2 / 3, c2 = t2 - (t2 / 3) * 3;
            if (c2 == 0) ws0[jj2] = wv1; else if (c2 == 1) ws1[jj2] = wv1; else ws2[jj2] = wv1;
        }
    }
    __syncthreads();

    // ---- MFMA: D = Q·K^T ----
    const int qrow = w * 16 + ln;
    short8 a0f = *(const short8*)&Qs[qrow * 8 + (quad ^ (qrow & 7))];
    short8 a1f = *(const short8*)&Qs[qrow * 8 + ((quad + 4) ^ (qrow & 7))];
    #pragma unroll
    for (int jsub = 0; jsub < 8; jsub++) {
        int krow = jsub * 16 + ln;
        short8 b0f = *(const short8*)&Ks[krow * 8 + (quad ^ (krow & 7))];
        short8 b1f = *(const short8*)&Ks[krow * 8 + ((quad + 4) ^ (krow & 7))];
        acc[jsub] = __builtin_amdgcn_mfma_f32_16x16x32_bf16(a0f, b0f, acc[jsub], 0, 0, 0);
        acc[jsub] = __builtin_amdgcn_mfma_f32_16x16x32_bf16(a1f, b1f, acc[jsub], 0, 0, 0);
    }

    // ---- wave-wide max (valid: any consistent m works with the exact slot merge) ----
    float m_r = acc[0][0];
    #pragma unroll
    for (int jsub = 0; jsub < 8; jsub++)
        #pragma unroll
        for (int r = 0; r < 4; r++) m_r = fmaxf(m_r, acc[jsub][r]);
    #pragma unroll
    for (int off = 1; off < 64; off <<= 1) m_r = fmaxf(m_r, __shfl_xor(m_r, off, 64));

    // ---- exp + weighted accumulate; per-lane partial per i-row r ----
    const unsigned int* udbase = udp + (((size_t)b * NN + i0 + w * 16 + quad * 4) * NN + jb + ln) * 2;
    float lr[4] = {0.f, 0.f, 0.f, 0.f};
    float A0[4] = {0.f, 0.f, 0.f, 0.f};
    float A1[4] = {0.f, 0.f, 0.f, 0.f};
    float A2[4] = {0.f, 0.f, 0.f, 0.f};
    #pragma unroll
    for (int jsub = 0; jsub < 8; jsub++) {
        float w0 = ws0[jsub * 16 + ln];
        float w1 = ws1[jsub * 16 + ln];
        float w2 = ws2[jsub * 16 + ln];
        #pragma unroll
        for (int r = 0; r < 4; r++) {
            uint2 U = *(const uint2*)&udbase[((size_t)r * NN + jsub * 16) * 2];
            float p = __expf(acc[jsub][r] - m_r);
            lr[r] += p;
            A0[r] = fmaf(p * bf2f((unsigned short)(U.x & 0xFFFF)), w0, A0[r]);
            A1[r] = fmaf(p * bf2f((unsigned short)(U.x >> 16)), w1, A1[r]);
            A2[r] = fmaf(p * bf2f((unsigned short)(U.y & 0xFFFF)), w2, A2[r]);
        }
    }

    // ---- reduce over ln (j) ----
    #pragma unroll
    for (int off = 1; off < 16; off <<= 1) {
        #pragma unroll
        for (int r = 0; r < 4; r++) {
            lr[r] += __shfl_xor(lr[r], off, 64);
            A0[r] += __shfl_xor(A0[r], off, 64);
            A1[r] += __shfl_xor(A1[r], off, 64);
            A2[r] += __shfl_xor(A2[r], off, 64);
        }
    }
    if (ln == 0) {
        #pragma unroll
        for (int r = 0; r < 4; r++) {
            int ig = i0 + w * 16 + quad * 4 + r;
            size_t o4 = (bh * NN + ig) * 4 + js;
            mp[o4] = m_r; lp[o4] = lr[r];
            a0p[o4] = A0[r]; a1p[o4] = A1[r]; a2p[o4] = A2[r];
        }
    }
}

// ---------------- K4: finalize — exact max-merge over js, sum heads ----------------
__global__ __launch_bounds__(256) void k_finalize(
        const float* __restrict__ mp, const float* __restrict__ lp,
        const float* __restrict__ a0p, const float* __restrict__ a1p,
        const float* __restrict__ a2p,
        const float* __restrict__ b1, const float* __restrict__ b2,
        const float* __restrict__ b3, float* __restrict__ out) {
    int idx = blockIdx.x * 256 + threadIdx.x;   // 4096
    int b = idx >> 9, i = idx & (NN - 1);
    float s0 = 0.f, s1 = 0.f, s2 = 0.f;
    #pragma unroll
    for (int h = 0; h < NH; h++) {
        size_t base = (((size_t)b * NH + h) * NN + i) * 4;
        f32x4 mv = *(const f32x4*)&mp[base];
        f32x4 lv = *(const f32x4*)&lp[base];
        f32x4 A0 = *(const f32x4*)&a0p[base];
        f32x4 A1 = *(const f32x4*)&a1p[base];
        f32x4 A2 = *(const f32x4*)&a2p[base];
        float M = fmaxf(fmaxf(mv[0], mv[1]), fmaxf(mv[2], mv[3]));
        float L = 0.f, c0 = 0.f, c1 = 0.f, c2 = 0.f;
        #pragma unroll
        for (int js = 0; js < 4; js++) {
            float e = __expf(mv[js] - M);
            L = fmaf(e, lv[js], L);
            c0 = fmaf(e, A0[js], c0);
            c1 = fmaf(e, A1[js], c1);
            c2 = fmaf(e, A2[js], c2);
        }
        float inv = 1.f / L;
        s0 = fmaf(c0, inv, s0);
        s1 = fmaf(c1, inv, s1);
        s2 = fmaf(c2, inv, s2);
    }
    float* op = out + (size_t)idx * 3;
    op[0] = s0 + b1[0];
    op[1] = s1 + b2[0];
    op[2] = s2 + b3[0];
}

extern "C" void kernel_launch(void* const* d_in, const int* in_sizes, int n_in,
                              void* d_out, int out_size, void* d_ws, size_t ws_size,
                              hipStream_t stream) {
    const float* query = (const float*)d_in[0];
    const float* bias  = (const float*)d_in[1];
    const float* pos   = (const float*)d_in[2];
    const float* Wq = (const float*)d_in[3];
    const float* bq = (const float*)d_in[4];
    const float* Wk = (const float*)d_in[5];
    const float* bk = (const float*)d_in[6];
    const float* Wv = (const float*)d_in[7];
    const float* bv = (const float*)d_in[8];
    const float* W1 = (const float*)d_in[9];
    const float* b1 = (const float*)d_in[10];
    const float* W2 = (const float*)d_in[11];
    const float* b2 = (const float*)d_in[12];
    const float* W3 = (const float*)d_in[13];
    const float* b3 = (const float*)d_in[14];
    float* out = (float*)d_out;

    char* p = (char*)d_ws;
    unsigned short* WT = (unsigned short*)p; p += (size_t)NCAT * EDIM * 2;      // 2.6 MB
    float* bcat = (float*)p;                 p += (size_t)NCAT * 4;
    unsigned short* Xb = (unsigned short*)p; p += (size_t)BSZ * NN * EDIM * 2;  // 6.3 MB
    unsigned short* qb = (unsigned short*)p; p += (size_t)BSZ * NH * NN * HD * 2;
    unsigned short* kb = (unsigned short*)p; p += (size_t)BSZ * NH * NN * HD * 2;
    float* vwb = (float*)p;                  p += (size_t)BSZ * NH * NN * 3 * 4;
    unsigned int* udp = (unsigned int*)p;    p += (size_t)BSZ * NN * NN * 8;    // 16.8 MB packed
    const size_t PSZ = (size_t)BSZ * NH * NN * 4;   // partial slots (b,h,i,js)
    float* mp  = (float*)p; p += PSZ * 4;
    float* lp  = (float*)p; p += PSZ * 4;
    float* a0p = (float*)p; p += PSZ * 4;
    float* a1p = (float*)p; p += PSZ * 4;
    float* a2p = (float*)p; p += PSZ * 4;

    k_prep<<<PREP_BLOCKS, 256, 0, stream>>>(query, pos, Wq, bq, Wk, bk, Wv, bv,
                                            W1, W2, W3, WT, bcat, Xb, udp);
    dim3 g2(64, 13);
    k_gemm_qkv<<<g2, 256, 0, stream>>>(Xb, WT, bcat, qb, kb, vwb);
    k_attn<<<BSZ * NH * 8 * 4, 256, 0, stream>>>(qb, kb, vwb, bias, udp,
                                                 mp, lp, a0p, a1p, a2p);
    k_finalize<<<BSZ * NN / 256, 256, 0, stream>>>(mp, lp, a0p, a1p, a2p, b1, b2, b3, out);
}

// Round 8
// 247.165 us; speedup vs baseline: 1.1662x; 1.0201x over previous
//
#include <hip/hip_runtime.h>
#include <math.h>

#define EDIM 768
#define NH 12
#define HD 64
#define BSZ 8
#define NN 512
#define NCAT 1664          // 768(q) + 768(k) + 36(vw) padded to 13*128

typedef short short8 __attribute__((ext_vector_type(8)));
typedef float f32x4 __attribute__((ext_vector_type(4)));

__device__ __forceinline__ unsigned short f2bf(float x) {
    unsigned int u = __float_as_uint(x);
    u = (u + 0x7FFF + ((u >> 16) & 1)) >> 16;   // RNE
    return (unsigned short)u;
}
__device__ __forceinline__ void gl2lds16(const void* g, void* l) {
    __builtin_amdgcn_global_load_lds(
        (const __attribute__((address_space(1))) unsigned int*)g,
        (__attribute__((address_space(3))) unsigned int*)l, 16, 0, 0);
}

// ---- prep block ranges (geometry section removed — attn computes it on the fly) ----
#define PB_TR_END   1152         // WT transpose for q/k (48 n-tiles x 24 e-tiles)
#define PB_VW_END   1260         // +108: WT vw columns (36*768/256)
#define PB_CVT_END  2796         // +1536: X fp32->bf16 (4096*96/256)
#define PB_BC_END   2803         // +7: bcat
#define PREP_BLOCKS 2838         // +35: WT padding rows zero

// ---------------- K1: fused prep ----------------
__global__ __launch_bounds__(256) void k_prep(
        const float* __restrict__ query,
        const float* __restrict__ Wq, const float* __restrict__ bq,
        const float* __restrict__ Wk, const float* __restrict__ bk,
        const float* __restrict__ Wv, const float* __restrict__ bv,
        const float* __restrict__ W1, const float* __restrict__ W2,
        const float* __restrict__ W3,
        unsigned short* __restrict__ WT, float* __restrict__ bcat,
        unsigned short* __restrict__ Xb) {
    __shared__ float sm[1536];
    const int bid = blockIdx.x;
    const int t = threadIdx.x;

    if (bid < PB_TR_END) {
        // WT[n][e] = W{q,k}[e][n mod 768] bf16, via LDS transpose
        float (*tile)[33] = (float(*)[33])sm;
        const int n0 = (bid % 48) * 32, e0 = (bid / 48) * 32;
        const float* src = (n0 < 768) ? Wq : Wk;
        const int ol0 = (n0 < 768) ? n0 : (n0 - 768);
        const int tx = t & 31, ty = t >> 5;
        #pragma unroll
        for (int s = 0; s < 4; s++)
            tile[ty + s * 8][tx] = src[(size_t)(e0 + ty + s * 8) * EDIM + ol0 + tx];
        __syncthreads();
        #pragma unroll
        for (int s = 0; s < 4; s++)
            WT[(size_t)(n0 + ty + s * 8) * EDIM + e0 + tx] = f2bf(tile[tx][ty + s * 8]);
    } else if (bid < PB_VW_END) {
        // WT vw columns: WT[1536+o2][e] = sum_d Wv[e][h*64+d]*Wc[h*64+d]
        int idx = (bid - PB_TR_END) * 256 + t;   // < 27648
        int o2 = idx / 768, e = idx - o2 * 768;
        int h = o2 / 3, c = o2 - (o2 / 3) * 3;
        const float* Wc = (c == 0) ? W1 : (c == 1) ? W2 : W3;
        const float4* wvp = (const float4*)(Wv + (size_t)e * EDIM + h * HD);
        const float4* wcp = (const float4*)(Wc + h * HD);
        float s = 0.f;
        #pragma unroll
        for (int d4 = 0; d4 < 16; d4++) {
            float4 a = wvp[d4], b = wcp[d4];
            s += a.x * b.x + a.y * b.y + a.z * b.z + a.w * b.w;
        }
        WT[(size_t)(1536 + o2) * EDIM + e] = f2bf(s);
    } else if (bid < PB_CVT_END) {
        // X fp32 (n,b,e) -> Xb[m][e] bf16
        int idx = (bid - PB_VW_END) * 256 + t;   // < 393216
        int m = idx / 96, e8 = (idx - (idx / 96) * 96) * 8;
        int b = m >> 9, i = m & (NN - 1);
        const float* src = query + ((size_t)i * BSZ + b) * EDIM + e8;
        float4 v0 = *(const float4*)src;
        float4 v1 = *(const float4*)(src + 4);
        unsigned int p0 = f2bf(v0.x) | ((unsigned int)f2bf(v0.y) << 16);
        unsigned int p1 = f2bf(v0.z) | ((unsigned int)f2bf(v0.w) << 16);
        unsigned int p2 = f2bf(v1.x) | ((unsigned int)f2bf(v1.y) << 16);
        unsigned int p3 = f2bf(v1.z) | ((unsigned int)f2bf(v1.w) << 16);
        uint4 pk = {p0, p1, p2, p3};
        *(uint4*)&Xb[(size_t)idx * 8] = pk;
    } else if (bid < PB_BC_END) {
        int o = (bid - PB_CVT_END) * 256 + t;
        if (o < NCAT) {
            float v = 0.f;
            if (o < 768) v = bq[o];
            else if (o < 1536) v = bk[o - 768];
            else if (o < 1572) {
                int o2 = o - 1536;
                int h = o2 / 3, c = o2 - (o2 / 3) * 3;
                const float* Wc = (c == 0) ? W1 : (c == 1) ? W2 : W3;
                float s = 0.f;
                for (int d = 0; d < HD; d++) s += bv[h * HD + d] * Wc[h * HD + d];
                v = s;
            }
            bcat[o] = v;
        }
    } else {
        int tid = (bid - PB_BC_END) * 256 + t;
        if (tid < 8832) {
            uint4 z = {0, 0, 0, 0};
            *(uint4*)&WT[(size_t)1572 * EDIM + (size_t)tid * 8] = z;
        }
    }
}

// ---------------- K2: bf16 MFMA GEMM (64x128 tile) ----------------
__global__ __launch_bounds__(256) void k_gemm_qkv(
        const unsigned short* __restrict__ Xb, const unsigned short* __restrict__ WT,
        const float* __restrict__ bcat,
        unsigned short* __restrict__ qb, unsigned short* __restrict__ kb,
        float* __restrict__ vwb) {
    __shared__ short As[8 * 64 * 8];    // 8 KB
    __shared__ short Bs[8 * 128 * 8];   // 16 KB
    const int t = threadIdx.x;
    const int m0 = blockIdx.x * 64, n0 = blockIdx.y * 128;
    const int w = t >> 6, lane = t & 63, quad = lane >> 4, ln = lane & 15;
    const int wm = (w & 1) * 32, wn = (w >> 1) * 64;

    f32x4 acc[2][4];
    #pragma unroll
    for (int mi = 0; mi < 2; mi++)
        #pragma unroll
        for (int ni = 0; ni < 4; ni++) acc[mi][ni] = (f32x4){0.f, 0.f, 0.f, 0.f};

    for (int k0 = 0; k0 < EDIM; k0 += 64) {
        __syncthreads();
        #pragma unroll
        for (int is = 0; is < 2; is++) {
            int slot = is * 256 + t;
            int g = slot >> 6, m = slot & 63;
            gl2lds16(Xb + (size_t)(m0 + m) * EDIM + k0 + g * 8, &As[(size_t)(is * 256 + w * 64) * 8]);
        }
        #pragma unroll
        for (int is = 0; is < 4; is++) {
            int slot = is * 256 + t;
            int g = slot >> 7, n = slot & 127;
            gl2lds16(WT + (size_t)(n0 + n) * EDIM + k0 + g * 8, &Bs[(size_t)(is * 256 + w * 64) * 8]);
        }
        __syncthreads();
        #pragma unroll
        for (int s = 0; s < 2; s++) {
            short8 af[2], bf[4];
            #pragma unroll
            for (int mi = 0; mi < 2; mi++)
                af[mi] = *(const short8*)&As[(size_t)((s * 4 + quad) * 64 + wm + mi * 16 + ln) * 8];
            #pragma unroll
            for (int ni = 0; ni < 4; ni++)
                bf[ni] = *(const short8*)&Bs[(size_t)((s * 4 + quad) * 128 + wn + ni * 16 + ln) * 8];
            #pragma unroll
            for (int mi = 0; mi < 2; mi++)
                #pragma unroll
                for (int ni = 0; ni < 4; ni++)
                    acc[mi][ni] = __builtin_amdgcn_mfma_f32_16x16x32_bf16(af[mi], bf[ni], acc[mi][ni], 0, 0, 0);
        }
    }

    #pragma unroll
    for (int mi = 0; mi < 2; mi++) {
        #pragma unroll
        for (int r = 0; r < 4; r++) {
            int mg = m0 + wm + mi * 16 + quad * 4 + r;
            int b_ = mg >> 9, i_ = mg & (NN - 1);
            #pragma unroll
            for (int ni = 0; ni < 4; ni++) {
                int o = n0 + wn + ni * 16 + ln;
                float val = acc[mi][ni][r] + bcat[o];
                if (o < 768) {
                    int h = o >> 6, d = o & 63;
                    qb[(((size_t)b_ * NH + h) * NN + i_) * HD + d] = f2bf(val * 0.125f);
                } else if (o < 1536) {
                    int o2 = o - 768;
                    int h = o2 >> 6, d = o2 & 63;
                    kb[(((size_t)b_ * NH + h) * NN + i_) * HD + d] = f2bf(val);
                } else if (o < 1572) {
                    int o2 = o - 1536;
                    int h = o2 / 3, c = o2 - (o2 / 3) * 3;
                    vwb[(((size_t)b_ * NH + h) * NN + i_) * 3 + c] = val;
                }
            }
        }
    }
}

// ---------------- K3: attention partials — lane=j orientation, on-the-fly geometry ----------------
// block = (h, js, it, b): 64 i x 128 j. A=Q, B=K -> C row = i = quad*4+r, col = j = ln.
// Geometry (unit delta / dist) recomputed from pos in registers — no ud table.
__global__ __launch_bounds__(256, 4) void k_attn(
        const unsigned short* __restrict__ qb, const unsigned short* __restrict__ kb,
        const float* __restrict__ vwb, const float* __restrict__ bias,
        const float* __restrict__ pos,
        float* __restrict__ mp, float* __restrict__ lp,
        float* __restrict__ a0p, float* __restrict__ a1p, float* __restrict__ a2p) {
    __shared__ uint4 Qs[64 * 8];    // 8 KB, unit = row*8 + (c ^ (row&7))
    __shared__ uint4 Ks[128 * 8];   // 16 KB, same swizzle
    __shared__ float ws0[128], ws1[128], ws2[128];
    __shared__ float pjx[128], pjy[128], pjz[128];
    __shared__ float pix[64], piy[64], piz[64];

    const int t = threadIdx.x;
    const int bid = blockIdx.x;
    const int h = bid % NH;
    const int r1 = bid / NH;            // [0,256)
    const int js = r1 & 3;
    const int it = (r1 >> 2) & 7;
    const int b = r1 >> 5;
    const int i0 = it * 64;
    const int jb = js * 128;
    const int w = t >> 6, lane = t & 63, quad = lane >> 4, ln = lane & 15;
    const size_t bh = (size_t)b * NH + h;

    // ---- coalesced global loads of Q (64x64) and K (128x64) tiles ----
    const uint4* qg = (const uint4*)(qb + (bh * NN + i0) * HD);   // 512 units
    const uint4* kg = (const uint4*)(kb + (bh * NN + jb) * HD);   // 1024 units
    const int rr = t >> 3, cc = t & 7;
    uint4 qv0 = qg[t];
    uint4 qv1 = qg[256 + t];
    uint4 kv0 = kg[t];
    uint4 kv1 = kg[256 + t];
    uint4 kv2 = kg[512 + t];
    uint4 kv3 = kg[768 + t];
    float wv0 = vwb[bh * (NN * 3) + (size_t)jb * 3 + t];
    float wv1 = (t < 128) ? vwb[bh * (NN * 3) + (size_t)jb * 3 + 256 + t] : 0.f;

    // ---- bias straight into MFMA accumulators (coalesced: 16 lanes x 4 rows) ----
    const float* bbase = bias + (bh * NN + i0 + w * 16 + quad * 4) * NN + jb + ln;
    f32x4 acc[8];
    #pragma unroll
    for (int jsub = 0; jsub < 8; jsub++)
        #pragma unroll
        for (int r = 0; r < 4; r++)
            acc[jsub][r] = bbase[r * NN + jsub * 16];

    // ---- position staging ----
    for (int idx = t; idx < 384; idx += 256) {
        float pv = pos[((size_t)b * NN + jb) * 3 + idx];
        int jj = idx / 3, c = idx - (idx / 3) * 3;
        if (c == 0) pjx[jj] = pv; else if (c == 1) pjy[jj] = pv; else pjz[jj] = pv;
    }
    if (t < 192) {
        float pv = pos[((size_t)b * NN + i0) * 3 + t];
        int ii = t / 3, c = t - (t / 3) * 3;
        if (c == 0) pix[ii] = pv; else if (c == 1) piy[ii] = pv; else piz[ii] = pv;
    }

    // ---- LDS writes (xor-swizzled) ----
    const int sw = cc ^ (rr & 7);
    Qs[rr * 8 + sw] = qv0;
    Qs[(rr + 32) * 8 + sw] = qv1;
    Ks[rr * 8 + sw] = kv0;
    Ks[(rr + 32) * 8 + sw] = kv1;
    Ks[(rr + 64) * 8 + sw] = kv2;
    Ks[(rr + 96) * 8 + sw] = kv3;
    {
        int jj = t / 3, c = t - (t / 3) * 3;
        if (c == 0) ws0[jj] = wv0; else if (c == 1) ws1[jj] = wv0; else ws2[jj] = wv0;
        if (t < 128) {
            int t2 = 256 + t;
            int jj2 = t2 / 3, c2 = t2 - (t2 / 3) * 3;
            if (c2 == 0) ws0[jj2] = wv1; else if (c2 == 1) ws1[jj2] = wv1; else ws2[jj2] = wv1;
        }
    }
    __syncthreads();

    // ---- MFMA: D = Q·K^T ----
    const int qrow = w * 16 + ln;
    short8 a0f = *(const short8*)&Qs[qrow * 8 + (quad ^ (qrow & 7))];
    short8 a1f = *(const short8*)&Qs[qrow * 8 + ((quad + 4) ^ (qrow & 7))];
    #pragma unroll
    for (int jsub = 0; jsub < 8; jsub++) {
        int krow = jsub * 16 + ln;
        short8 b0f = *(const short8*)&Ks[krow * 8 + (quad ^ (krow & 7))];
        short8 b1f = *(const short8*)&Ks[krow * 8 + ((quad + 4) ^ (krow & 7))];
        acc[jsub] = __builtin_amdgcn_mfma_f32_16x16x32_bf16(a0f, b0f, acc[jsub], 0, 0, 0);
        acc[jsub] = __builtin_amdgcn_mfma_f32_16x16x32_bf16(a1f, b1f, acc[jsub], 0, 0, 0);
    }

    // ---- wave-wide max (valid: any consistent m works with the exact slot merge) ----
    float m_r = acc[0][0];
    #pragma unroll
    for (int jsub = 0; jsub < 8; jsub++)
        #pragma unroll
        for (int r = 0; r < 4; r++) m_r = fmaxf(m_r, acc[jsub][r]);
    #pragma unroll
    for (int off = 1; off < 64; off <<= 1) m_r = fmaxf(m_r, __shfl_xor(m_r, off, 64));

    // ---- exp + geometry-on-the-fly weighted accumulate ----
    const int irbase = w * 16 + quad * 4;
    float lr[4] = {0.f, 0.f, 0.f, 0.f};
    float A0[4] = {0.f, 0.f, 0.f, 0.f};
    float A1[4] = {0.f, 0.f, 0.f, 0.f};
    float A2[4] = {0.f, 0.f, 0.f, 0.f};
    #pragma unroll
    for (int jsub = 0; jsub < 8; jsub++) {
        const int jl = jsub * 16 + ln;
        float w0 = ws0[jl], w1 = ws1[jl], w2 = ws2[jl];
        float px = pjx[jl], py = pjy[jl], pz = pjz[jl];
        #pragma unroll
        for (int r = 0; r < 4; r++) {
            float dx = px - pix[irbase + r];
            float dy = py - piy[irbase + r];
            float dz = pz - piz[irbase + r];
            float d2 = fmaf(dx, dx, fmaf(dy, dy, dz * dz));
            float inv = __builtin_amdgcn_rcpf(__builtin_amdgcn_sqrtf(d2) + 1e-5f);
            float p = __expf(acc[jsub][r] - m_r);
            float pi = p * inv;
            lr[r] += p;
            A0[r] = fmaf(pi * dx, w0, A0[r]);
            A1[r] = fmaf(pi * dy, w1, A1[r]);
            A2[r] = fmaf(pi * dz, w2, A2[r]);
        }
    }

    // ---- reduce over ln (j) ----
    #pragma unroll
    for (int off = 1; off < 16; off <<= 1) {
        #pragma unroll
        for (int r = 0; r < 4; r++) {
            lr[r] += __shfl_xor(lr[r], off, 64);
            A0[r] += __shfl_xor(A0[r], off, 64);
            A1[r] += __shfl_xor(A1[r], off, 64);
            A2[r] += __shfl_xor(A2[r], off, 64);
        }
    }
    if (ln == 0) {
        #pragma unroll
        for (int r = 0; r < 4; r++) {
            int ig = i0 + irbase + r;
            size_t o4 = (bh * NN + ig) * 4 + js;
            mp[o4] = m_r; lp[o4] = lr[r];
            a0p[o4] = A0[r]; a1p[o4] = A1[r]; a2p[o4] = A2[r];
        }
    }
}

// ---------------- K4: finalize — exact max-merge over js, sum heads ----------------
__global__ __launch_bounds__(256) void k_finalize(
        const float* __restrict__ mp, const float* __restrict__ lp,
        const float* __restrict__ a0p, const float* __restrict__ a1p,
        const float* __restrict__ a2p,
        const float* __restrict__ b1, const float* __restrict__ b2,
        const float* __restrict__ b3, float* __restrict__ out) {
    int idx = blockIdx.x * 256 + threadIdx.x;   // 4096
    int b = idx >> 9, i = idx & (NN - 1);
    float s0 = 0.f, s1 = 0.f, s2 = 0.f;
    #pragma unroll
    for (int h = 0; h < NH; h++) {
        size_t base = (((size_t)b * NH + h) * NN + i) * 4;
        f32x4 mv = *(const f32x4*)&mp[base];
        f32x4 lv = *(const f32x4*)&lp[base];
        f32x4 A0 = *(const f32x4*)&a0p[base];
        f32x4 A1 = *(const f32x4*)&a1p[base];
        f32x4 A2 = *(const f32x4*)&a2p[base];
        float M = fmaxf(fmaxf(mv[0], mv[1]), fmaxf(mv[2], mv[3]));
        float L = 0.f, c0 = 0.f, c1 = 0.f, c2 = 0.f;
        #pragma unroll
        for (int js = 0; js < 4; js++) {
            float e = __expf(mv[js] - M);
            L = fmaf(e, lv[js], L);
            c0 = fmaf(e, A0[js], c0);
            c1 = fmaf(e, A1[js], c1);
            c2 = fmaf(e, A2[js], c2);
        }
        float inv = 1.f / L;
        s0 = fmaf(c0, inv, s0);
        s1 = fmaf(c1, inv, s1);
        s2 = fmaf(c2, inv, s2);
    }
    float* op = out + (size_t)idx * 3;
    op[0] = s0 + b1[0];
    op[1] = s1 + b2[0];
    op[2] = s2 + b3[0];
}

extern "C" void kernel_launch(void* const* d_in, const int* in_sizes, int n_in,
                              void* d_out, int out_size, void* d_ws, size_t ws_size,
                              hipStream_t stream) {
    const float* query = (const float*)d_in[0];
    const float* bias  = (const float*)d_in[1];
    const float* pos   = (const float*)d_in[2];
    const float* Wq = (const float*)d_in[3];
    const float* bq = (const float*)d_in[4];
    const float* Wk = (const float*)d_in[5];
    const float* bk = (const float*)d_in[6];
    const float* Wv = (const float*)d_in[7];
    const float* bv = (const float*)d_in[8];
    const float* W1 = (const float*)d_in[9];
    const float* b1 = (const float*)d_in[10];
    const float* W2 = (const float*)d_in[11];
    const float* b2 = (const float*)d_in[12];
    const float* W3 = (const float*)d_in[13];
    const float* b3 = (const float*)d_in[14];
    float* out = (float*)d_out;

    char* p = (char*)d_ws;
    unsigned short* WT = (unsigned short*)p; p += (size_t)NCAT * EDIM * 2;      // 2.6 MB
    float* bcat = (float*)p;                 p += (size_t)NCAT * 4;
    unsigned short* Xb = (unsigned short*)p; p += (size_t)BSZ * NN * EDIM * 2;  // 6.3 MB
    unsigned short* qb = (unsigned short*)p; p += (size_t)BSZ * NH * NN * HD * 2;
    unsigned short* kb = (unsigned short*)p; p += (size_t)BSZ * NH * NN * HD * 2;
    float* vwb = (float*)p;                  p += (size_t)BSZ * NH * NN * 3 * 4;
    const size_t PSZ = (size_t)BSZ * NH * NN * 4;   // partial slots (b,h,i,js)
    float* mp  = (float*)p; p += PSZ * 4;
    float* lp  = (float*)p; p += PSZ * 4;
    float* a0p = (float*)p; p += PSZ * 4;
    float* a1p = (float*)p; p += PSZ * 4;
    float* a2p = (float*)p; p += PSZ * 4;

    k_prep<<<PREP_BLOCKS, 256, 0, stream>>>(query, Wq, bq, Wk, bk, Wv, bv,
                                            W1, W2, W3, WT, bcat, Xb);
    dim3 g2(64, 13);
    k_gemm_qkv<<<g2, 256, 0, stream>>>(Xb, WT, bcat, qb, kb, vwb);
    k_attn<<<BSZ * NH * 8 * 4, 256, 0, stream>>>(qb, kb, vwb, bias, pos,
                                                 mp, lp, a0p, a1p, a2p);
    k_finalize<<<BSZ * NN / 256, 256, 0, stream>>>(mp, lp, a0p, a1p, a2p, b1, b2, b3, out);
}

// Round 9
// 244.179 us; speedup vs baseline: 1.1805x; 1.0122x over previous
//
#include <hip/hip_runtime.h>
#include <math.h>

#define EDIM 768
#define NH 12
#define HD 64
#define BSZ 8
#define NN 512
#define NCAT 1664          // 768(q) + 768(k) + 36(vw) padded to 13*128

typedef short short8 __attribute__((ext_vector_type(8)));
typedef float f32x4 __attribute__((ext_vector_type(4)));

__device__ __forceinline__ unsigned short f2bf(float x) {
    unsigned int u = __float_as_uint(x);
    u = (u + 0x7FFF + ((u >> 16) & 1)) >> 16;   // RNE
    return (unsigned short)u;
}
__device__ __forceinline__ void gl2lds16(const void* g, void* l) {
    __builtin_amdgcn_global_load_lds(
        (const __attribute__((address_space(1))) unsigned int*)g,
        (__attribute__((address_space(3))) unsigned int*)l, 16, 0, 0);
}

// ---- prep block ranges ----
#define PB_TR_END   1152         // WT transpose for q/k (48 n-tiles x 24 e-tiles)
#define PB_VW_END   1260         // +108: WT vw columns (36*768/256)
#define PB_CVT_END  2028         // +768: X fp32->bf16 (2 units/thread)
#define PB_BC_END   2035         // +7: bcat
#define PREP_BLOCKS 2070         // +35: WT padding rows zero

// ---------------- K1: fused prep ----------------
__global__ __launch_bounds__(256) void k_prep(
        const float* __restrict__ query,
        const float* __restrict__ Wq, const float* __restrict__ bq,
        const float* __restrict__ Wk, const float* __restrict__ bk,
        const float* __restrict__ Wv, const float* __restrict__ bv,
        const float* __restrict__ W1, const float* __restrict__ W2,
        const float* __restrict__ W3,
        unsigned short* __restrict__ WT, float* __restrict__ bcat,
        unsigned short* __restrict__ Xb) {
    __shared__ float sm[1536];
    const int bid = blockIdx.x;
    const int t = threadIdx.x;

    if (bid < PB_TR_END) {
        // WT[n][e] = W{q,k}[e][n mod 768] bf16 (q-part pre-scaled by 0.125)
        float (*tile)[33] = (float(*)[33])sm;
        const int n0 = (bid % 48) * 32, e0 = (bid / 48) * 32;
        const float* src = (n0 < 768) ? Wq : Wk;
        const float sc = (n0 < 768) ? 0.125f : 1.0f;
        const int ol0 = (n0 < 768) ? n0 : (n0 - 768);
        const int tx = t & 31, ty = t >> 5;
        #pragma unroll
        for (int s = 0; s < 4; s++)
            tile[ty + s * 8][tx] = src[(size_t)(e0 + ty + s * 8) * EDIM + ol0 + tx];
        __syncthreads();
        #pragma unroll
        for (int s = 0; s < 4; s++)
            WT[(size_t)(n0 + ty + s * 8) * EDIM + e0 + tx] = f2bf(tile[tx][ty + s * 8] * sc);
    } else if (bid < PB_VW_END) {
        // WT vw columns: WT[1536+o2][e] = sum_d Wv[e][h*64+d]*Wc[h*64+d]
        int idx = (bid - PB_TR_END) * 256 + t;   // < 27648
        int o2 = idx / 768, e = idx - o2 * 768;
        int h = o2 / 3, c = o2 - (o2 / 3) * 3;
        const float* Wc = (c == 0) ? W1 : (c == 1) ? W2 : W3;
        const float4* wvp = (const float4*)(Wv + (size_t)e * EDIM + h * HD);
        const float4* wcp = (const float4*)(Wc + h * HD);
        float s = 0.f;
        #pragma unroll
        for (int d4 = 0; d4 < 16; d4++) {
            float4 a = wvp[d4], b = wcp[d4];
            s += a.x * b.x + a.y * b.y + a.z * b.z + a.w * b.w;
        }
        WT[(size_t)(1536 + o2) * EDIM + e] = f2bf(s);
    } else if (bid < PB_CVT_END) {
        // X fp32 (n,b,e) -> Xb[m][e] bf16; 2 units per thread (half-split)
        int base = (bid - PB_VW_END) * 256 + t;   // < 196608
        #pragma unroll
        for (int half = 0; half < 2; half++) {
            int idx = base + half * 196608;
            int m = idx / 96, e8 = (idx - (idx / 96) * 96) * 8;
            int b = m >> 9, i = m & (NN - 1);
            const float* src = query + ((size_t)i * BSZ + b) * EDIM + e8;
            float4 v0 = *(const float4*)src;
            float4 v1 = *(const float4*)(src + 4);
            unsigned int p0 = f2bf(v0.x) | ((unsigned int)f2bf(v0.y) << 16);
            unsigned int p1 = f2bf(v0.z) | ((unsigned int)f2bf(v0.w) << 16);
            unsigned int p2 = f2bf(v1.x) | ((unsigned int)f2bf(v1.y) << 16);
            unsigned int p3 = f2bf(v1.z) | ((unsigned int)f2bf(v1.w) << 16);
            uint4 pk = {p0, p1, p2, p3};
            *(uint4*)&Xb[(size_t)idx * 8] = pk;
        }
    } else if (bid < PB_BC_END) {
        int o = (bid - PB_CVT_END) * 256 + t;
        if (o < NCAT) {
            float v = 0.f;
            if (o < 768) v = bq[o] * 0.125f;
            else if (o < 1536) v = bk[o - 768];
            else if (o < 1572) {
                int o2 = o - 1536;
                int h = o2 / 3, c = o2 - (o2 / 3) * 3;
                const float* Wc = (c == 0) ? W1 : (c == 1) ? W2 : W3;
                float s = 0.f;
                for (int d = 0; d < HD; d++) s += bv[h * HD + d] * Wc[h * HD + d];
                v = s;
            }
            bcat[o] = v;
        }
    } else {
        int tid = (bid - PB_BC_END) * 256 + t;
        if (tid < 8832) {
            uint4 z = {0, 0, 0, 0};
            *(uint4*)&WT[(size_t)1572 * EDIM + (size_t)tid * 8] = z;
        }
    }
}

// ---------------- K2: bf16 MFMA GEMM (64x128 tile) ----------------
__global__ __launch_bounds__(256) void k_gemm_qkv(
        const unsigned short* __restrict__ Xb, const unsigned short* __restrict__ WT,
        const float* __restrict__ bcat,
        unsigned short* __restrict__ qb, unsigned short* __restrict__ kb,
        float* __restrict__ vwb) {
    __shared__ short As[8 * 64 * 8];    // 8 KB
    __shared__ short Bs[8 * 128 * 8];   // 16 KB
    const int t = threadIdx.x;
    const int m0 = blockIdx.x * 64, n0 = blockIdx.y * 128;
    const int w = t >> 6, lane = t & 63, quad = lane >> 4, ln = lane & 15;
    const int wm = (w & 1) * 32, wn = (w >> 1) * 64;

    f32x4 acc[2][4];
    #pragma unroll
    for (int mi = 0; mi < 2; mi++)
        #pragma unroll
        for (int ni = 0; ni < 4; ni++) acc[mi][ni] = (f32x4){0.f, 0.f, 0.f, 0.f};

    for (int k0 = 0; k0 < EDIM; k0 += 64) {
        __syncthreads();
        #pragma unroll
        for (int is = 0; is < 2; is++) {
            int slot = is * 256 + t;
            int g = slot >> 6, m = slot & 63;
            gl2lds16(Xb + (size_t)(m0 + m) * EDIM + k0 + g * 8, &As[(size_t)(is * 256 + w * 64) * 8]);
        }
        #pragma unroll
        for (int is = 0; is < 4; is++) {
            int slot = is * 256 + t;
            int g = slot >> 7, n = slot & 127;
            gl2lds16(WT + (size_t)(n0 + n) * EDIM + k0 + g * 8, &Bs[(size_t)(is * 256 + w * 64) * 8]);
        }
        __syncthreads();
        #pragma unroll
        for (int s = 0; s < 2; s++) {
            short8 af[2], bf[4];
            #pragma unroll
            for (int mi = 0; mi < 2; mi++)
                af[mi] = *(const short8*)&As[(size_t)((s * 4 + quad) * 64 + wm + mi * 16 + ln) * 8];
            #pragma unroll
            for (int ni = 0; ni < 4; ni++)
                bf[ni] = *(const short8*)&Bs[(size_t)((s * 4 + quad) * 128 + wn + ni * 16 + ln) * 8];
            #pragma unroll
            for (int mi = 0; mi < 2; mi++)
                #pragma unroll
                for (int ni = 0; ni < 4; ni++)
                    acc[mi][ni] = __builtin_amdgcn_mfma_f32_16x16x32_bf16(af[mi], bf[ni], acc[mi][ni], 0, 0, 0);
        }
    }

    #pragma unroll
    for (int mi = 0; mi < 2; mi++) {
        #pragma unroll
        for (int r = 0; r < 4; r++) {
            int mg = m0 + wm + mi * 16 + quad * 4 + r;
            int b_ = mg >> 9, i_ = mg & (NN - 1);
            #pragma unroll
            for (int ni = 0; ni < 4; ni++) {
                int o = n0 + wn + ni * 16 + ln;
                float val = acc[mi][ni][r] + bcat[o];
                if (o < 768) {
                    int h = o >> 6, d = o & 63;
                    qb[(((size_t)b_ * NH + h) * NN + i_) * HD + d] = f2bf(val);  // scale folded into WT/bcat
                } else if (o < 1536) {
                    int o2 = o - 768;
                    int h = o2 >> 6, d = o2 & 63;
                    kb[(((size_t)b_ * NH + h) * NN + i_) * HD + d] = f2bf(val);
                } else if (o < 1572) {
                    int o2 = o - 1536;
                    int h = o2 / 3, c = o2 - (o2 / 3) * 3;
                    vwb[(((size_t)b_ * NH + h) * NN + i_) * 3 + c] = val;
                }
            }
        }
    }
}

// ---------------- K3: attention partials — lane=j, q direct from global, no Qs LDS ----------------
__global__ __launch_bounds__(256, 6) void k_attn(
        const unsigned short* __restrict__ qb, const unsigned short* __restrict__ kb,
        const float* __restrict__ vwb, const float* __restrict__ bias,
        const float* __restrict__ pos,
        float* __restrict__ mp, float* __restrict__ lp,
        float* __restrict__ a0p, float* __restrict__ a1p, float* __restrict__ a2p) {
    __shared__ uint4 Ks[128 * 8];   // 16 KB, unit = row*8 + (c ^ (row&7))
    __shared__ float ws0[128], ws1[128], ws2[128];
    __shared__ float pjx[128], pjy[128], pjz[128];
    __shared__ float pix[64], piy[64], piz[64];

    const int t = threadIdx.x;
    const int bid = blockIdx.x;
    const int h = bid % NH;
    const int r1 = bid / NH;            // [0,256)
    const int js = r1 & 3;
    const int it = (r1 >> 2) & 7;
    const int b = r1 >> 5;
    const int i0 = it * 64;
    const int jb = js * 128;
    const int w = t >> 6, lane = t & 63, quad = lane >> 4, ln = lane & 15;
    const size_t bh = (size_t)b * NH + h;

    // ---- coalesced global loads of K (128x64) tile ----
    const uint4* kg = (const uint4*)(kb + (bh * NN + jb) * HD);   // 1024 units
    const int rr = t >> 3, cc = t & 7;
    uint4 kv0 = kg[t];
    uint4 kv1 = kg[256 + t];
    uint4 kv2 = kg[512 + t];
    uint4 kv3 = kg[768 + t];
    float wv0 = vwb[bh * (NN * 3) + (size_t)jb * 3 + t];
    float wv1 = (t < 128) ? vwb[bh * (NN * 3) + (size_t)jb * 3 + 256 + t] : 0.f;

    // ---- q fragments straight from global (A-frag = 16 contiguous bytes) ----
    const unsigned short* qrow = qb + (bh * NN + i0 + w * 16 + ln) * HD;
    short8 a0f = *(const short8*)(qrow + quad * 8);
    short8 a1f = *(const short8*)(qrow + 32 + quad * 8);

    // ---- bias straight into MFMA accumulators (coalesced: 16 lanes x 4 rows) ----
    const float* bbase = bias + (bh * NN + i0 + w * 16 + quad * 4) * NN + jb + ln;
    f32x4 acc[8];
    #pragma unroll
    for (int jsub = 0; jsub < 8; jsub++)
        #pragma unroll
        for (int r = 0; r < 4; r++)
            acc[jsub][r] = bbase[r * NN + jsub * 16];

    // ---- position staging ----
    for (int idx = t; idx < 384; idx += 256) {
        float pv = pos[((size_t)b * NN + jb) * 3 + idx];
        int jj = idx / 3, c = idx - (idx / 3) * 3;
        if (c == 0) pjx[jj] = pv; else if (c == 1) pjy[jj] = pv; else pjz[jj] = pv;
    }
    if (t < 192) {
        float pv = pos[((size_t)b * NN + i0) * 3 + t];
        int ii = t / 3, c = t - (t / 3) * 3;
        if (c == 0) pix[ii] = pv; else if (c == 1) piy[ii] = pv; else piz[ii] = pv;
    }

    // ---- LDS writes (xor-swizzled) ----
    const int sw = cc ^ (rr & 7);
    Ks[rr * 8 + sw] = kv0;
    Ks[(rr + 32) * 8 + sw] = kv1;
    Ks[(rr + 64) * 8 + sw] = kv2;
    Ks[(rr + 96) * 8 + sw] = kv3;
    {
        int jj = t / 3, c = t - (t / 3) * 3;
        if (c == 0) ws0[jj] = wv0; else if (c == 1) ws1[jj] = wv0; else ws2[jj] = wv0;
        if (t < 128) {
            int t2 = 256 + t;
            int jj2 = t2 / 3, c2 = t2 - (t2 / 3) * 3;
            if (c2 == 0) ws0[jj2] = wv1; else if (c2 == 1) ws1[jj2] = wv1; else ws2[jj2] = wv1;
        }
    }
    __syncthreads();

    // ---- MFMA: D = Q·K^T ----
    #pragma unroll
    for (int jsub = 0; jsub < 8; jsub++) {
        int krow = jsub * 16 + ln;
        short8 b0f = *(const short8*)&Ks[krow * 8 + (quad ^ (krow & 7))];
        short8 b1f = *(const short8*)&Ks[krow * 8 + ((quad + 4) ^ (krow & 7))];
        acc[jsub] = __builtin_amdgcn_mfma_f32_16x16x32_bf16(a0f, b0f, acc[jsub], 0, 0, 0);
        acc[jsub] = __builtin_amdgcn_mfma_f32_16x16x32_bf16(a1f, b1f, acc[jsub], 0, 0, 0);
    }

    // ---- wave-wide max (any consistent m is valid with the exact slot merge) ----
    float m_r = acc[0][0];
    #pragma unroll
    for (int jsub = 0; jsub < 8; jsub++)
        #pragma unroll
        for (int r = 0; r < 4; r++) m_r = fmaxf(m_r, acc[jsub][r]);
    #pragma unroll
    for (int off = 1; off < 64; off <<= 1) m_r = fmaxf(m_r, __shfl_xor(m_r, off, 64));

    // ---- exp + geometry-on-the-fly weighted accumulate ----
    const int irbase = w * 16 + quad * 4;
    float lr[4] = {0.f, 0.f, 0.f, 0.f};
    float A0[4] = {0.f, 0.f, 0.f, 0.f};
    float A1[4] = {0.f, 0.f, 0.f, 0.f};
    float A2[4] = {0.f, 0.f, 0.f, 0.f};
    #pragma unroll
    for (int jsub = 0; jsub < 8; jsub++) {
        const int jl = jsub * 16 + ln;
        float w0 = ws0[jl], w1 = ws1[jl], w2 = ws2[jl];
        float px = pjx[jl], py = pjy[jl], pz = pjz[jl];
        #pragma unroll
        for (int r = 0; r < 4; r++) {
            float dx = px - pix[irbase + r];
            float dy = py - piy[irbase + r];
            float dz = pz - piz[irbase + r];
            float d2 = fmaf(dx, dx, fmaf(dy, dy, dz * dz));
            float inv = __builtin_amdgcn_rcpf(__builtin_amdgcn_sqrtf(d2) + 1e-5f);
            float p = __expf(acc[jsub][r] - m_r);
            float pi = p * inv;
            lr[r] += p;
            A0[r] = fmaf(pi * dx, w0, A0[r]);
            A1[r] = fmaf(pi * dy, w1, A1[r]);
            A2[r] = fmaf(pi * dz, w2, A2[r]);
        }
    }

    // ---- reduce over ln (j) ----
    #pragma unroll
    for (int off = 1; off < 16; off <<= 1) {
        #pragma unroll
        for (int r = 0; r < 4; r++) {
            lr[r] += __shfl_xor(lr[r], off, 64);
            A0[r] += __shfl_xor(A0[r], off, 64);
            A1[r] += __shfl_xor(A1[r], off, 64);
            A2[r] += __shfl_xor(A2[r], off, 64);
        }
    }
    if (ln == 0) {
        #pragma unroll
        for (int r = 0; r < 4; r++) {
            int ig = i0 + irbase + r;
            size_t o4 = (bh * NN + ig) * 4 + js;
            mp[o4] = m_r; lp[o4] = lr[r];
            a0p[o4] = A0[r]; a1p[o4] = A1[r]; a2p[o4] = A2[r];
        }
    }
}

// ---------------- K4: finalize — exact max-merge over js, sum heads ----------------
__global__ __launch_bounds__(256) void k_finalize(
        const float* __restrict__ mp, const float* __restrict__ lp,
        const float* __restrict__ a0p, const float* __restrict__ a1p,
        const float* __restrict__ a2p,
        const float* __restrict__ b1, const float* __restrict__ b2,
        const float* __restrict__ b3, float* __restrict__ out) {
    int idx = blockIdx.x * 256 + threadIdx.x;   // 4096
    int b = idx >> 9, i = idx & (NN - 1);
    float s0 = 0.f, s1 = 0.f, s2 = 0.f;
    #pragma unroll
    for (int h = 0; h < NH; h++) {
        size_t base = (((size_t)b * NH + h) * NN + i) * 4;
        f32x4 mv = *(const f32x4*)&mp[base];
        f32x4 lv = *(const f32x4*)&lp[base];
        f32x4 A0 = *(const f32x4*)&a0p[base];
        f32x4 A1 = *(const f32x4*)&a1p[base];
        f32x4 A2 = *(const f32x4*)&a2p[base];
        float M = fmaxf(fmaxf(mv[0], mv[1]), fmaxf(mv[2], mv[3]));
        float L = 0.f, c0 = 0.f, c1 = 0.f, c2 = 0.f;
        #pragma unroll
        for (int js = 0; js < 4; js++) {
            float e = __expf(mv[js] - M);
            L = fmaf(e, lv[js], L);
            c0 = fmaf(e, A0[js], c0);
            c1 = fmaf(e, A1[js], c1);
            c2 = fmaf(e, A2[js], c2);
        }
        float inv = 1.f / L;
        s0 = fmaf(c0, inv, s0);
        s1 = fmaf(c1, inv, s1);
        s2 = fmaf(c2, inv, s2);
    }
    float* op = out + (size_t)idx * 3;
    op[0] = s0 + b1[0];
    op[1] = s1 + b2[0];
    op[2] = s2 + b3[0];
}

extern "C" void kernel_launch(void* const* d_in, const int* in_sizes, int n_in,
                              void* d_out, int out_size, void* d_ws, size_t ws_size,
                              hipStream_t stream) {
    const float* query = (const float*)d_in[0];
    const float* bias  = (const float*)d_in[1];
    const float* pos   = (const float*)d_in[2];
    const float* Wq = (const float*)d_in[3];
    const float* bq = (const float*)d_in[4];
    const float* Wk = (const float*)d_in[5];
    const float* bk = (const float*)d_in[6];
    const float* Wv = (const float*)d_in[7];
    const float* bv = (const float*)d_in[8];
    const float* W1 = (const float*)d_in[9];
    const float* b1 = (const float*)d_in[10];
    const float* W2 = (const float*)d_in[11];
    const float* b2 = (const float*)d_in[12];
    const float* W3 = (const float*)d_in[13];
    const float* b3 = (const float*)d_in[14];
    float* out = (float*)d_out;

    char* p = (char*)d_ws;
    unsigned short* WT = (unsigned short*)p; p += (size_t)NCAT * EDIM * 2;      // 2.6 MB
    float* bcat = (float*)p;                 p += (size_t)NCAT * 4;
    unsigned short* Xb = (unsigned short*)p; p += (size_t)BSZ * NN * EDIM * 2;  // 6.3 MB
    unsigned short* qb = (unsigned short*)p; p += (size_t)BSZ * NH * NN * HD * 2;
    unsigned short* kb = (unsigned short*)p; p += (size_t)BSZ * NH * NN * HD * 2;
    float* vwb = (float*)p;                  p += (size_t)BSZ * NH * NN * 3 * 4;
    const size_t PSZ = (size_t)BSZ * NH * NN * 4;   // partial slots (b,h,i,js)
    float* mp  = (float*)p; p += PSZ * 4;
    float* lp  = (float*)p; p += PSZ * 4;
    float* a0p = (float*)p; p += PSZ * 4;
    float* a1p = (float*)p; p += PSZ * 4;
    float* a2p = (float*)p; p += PSZ * 4;

    k_prep<<<PREP_BLOCKS, 256, 0, stream>>>(query, Wq, bq, Wk, bk, Wv, bv,
                                            W1, W2, W3, WT, bcat, Xb);
    dim3 g2(64, 13);
    k_gemm_qkv<<<g2, 256, 0, stream>>>(Xb, WT, bcat, qb, kb, vwb);
    k_attn<<<BSZ * NH * 8 * 4, 256, 0, stream>>>(qb, kb, vwb, bias, pos,
                                                 mp, lp, a0p, a1p, a2p);
    k_finalize<<<BSZ * NN / 256, 256, 0, stream>>>(mp, lp, a0p, a1p, a2p, b1, b2, b3, out);
}